// Round 3
// baseline (3227.175 us; speedup 1.0000x reference)
//
#include <hip/hip_runtime.h>
#include <hip/hip_bf16.h>

// ---------------------------------------------------------------------------
// Positional encoding value for channel c, token t (t = h*64 + w)
// pe[4i+0]=sin(w*div_i) pe[4i+1]=cos(w*div_i) pe[4i+2]=sin(h*div_i) pe[4i+3]=cos(h*div_i)
// div_i = exp(-i * ln(10000)/64)
// ---------------------------------------------------------------------------
__device__ __forceinline__ float pe_val(int c, int t) {
    int h = t >> 6, w = t & 63;
    int i = c >> 2, j = c & 3;
    float div = expf(-0.14391156831212787f * (float)i);
    float arg = ((j < 2) ? (float)w : (float)h) * div;
    return (j & 1) ? cosf(arg) : sinf(arg);
}

// ---------------------------------------------------------------------------
// Encode: feat (4,256,4096) f32 -> X[b,t,c], P2[b',t,c] f32 with PE added.
// sel=0 (ref): X batch n,   P2 batch 4+n
// sel=1 (src): X batch 4+n, P2 batch n
// ---------------------------------------------------------------------------
__global__ __launch_bounds__(1024) void encode_kernel(const float* __restrict__ ref,
                                                      const float* __restrict__ src,
                                                      float* __restrict__ X,
                                                      float* __restrict__ P2) {
    __shared__ float tile[32][33];
    int n = blockIdx.z >> 1, sel = blockIdx.z & 1;
    const float* f = sel ? src : ref;
    int t = blockIdx.x * 32 + threadIdx.x;
    int c = blockIdx.y * 32 + threadIdx.y;
    float v = f[((size_t)n * 256 + c) * 4096 + t] + pe_val(c, t);
    tile[threadIdx.y][threadIdx.x] = v;
    __syncthreads();
    int tt = blockIdx.x * 32 + threadIdx.y;
    int cc = blockIdx.y * 32 + threadIdx.x;
    float o = tile[threadIdx.x][threadIdx.y];
    int bx = sel ? 4 + n : n;
    int bp = sel ? n : 4 + n;
    X [((size_t)bx * 4096 + tt) * 256 + cc] = o;
    P2[((size_t)bp * 4096 + tt) * 256 + cc] = o;
}

// ---------------------------------------------------------------------------
// GEMM: C[M=32768, N] = epi(A[M,K] @ W[K,N] + bias)
// EPI: 0 = none, 1 = relu, 2 = in-place residual (C += result)
// ---------------------------------------------------------------------------
template <int EPI>
__global__ __launch_bounds__(256) void gemm_epi(const float* __restrict__ A,
                                                const float* __restrict__ W,
                                                const float* __restrict__ bias,
                                                float* __restrict__ C,
                                                int N, int K) {
    __shared__ float As[16][68];
    __shared__ float Bs[16][64];
    int tid = threadIdx.x;
    int bm = blockIdx.y * 64;
    int bn = blockIdx.x * 64;
    int tx = tid & 15;   // n
    int ty = tid >> 4;   // m
    float acc[4][4] = {};
    int ar = tid >> 2;
    int ac = (tid & 3) * 4;
    int wr = tid >> 4;
    int wc = (tid & 15) * 4;

    for (int k0 = 0; k0 < K; k0 += 16) {
        float4 av = *(const float4*)(A + (size_t)(bm + ar) * K + k0 + ac);
        As[ac + 0][ar] = av.x;
        As[ac + 1][ar] = av.y;
        As[ac + 2][ar] = av.z;
        As[ac + 3][ar] = av.w;
        float4 wv = *(const float4*)(W + (size_t)(k0 + wr) * N + bn + wc);
        *(float4*)&Bs[wr][wc] = wv;
        __syncthreads();
#pragma unroll
        for (int kk = 0; kk < 16; ++kk) {
            float4 a = *(float4*)&As[kk][ty * 4];
            float4 b = *(float4*)&Bs[kk][tx * 4];
            acc[0][0] += a.x * b.x; acc[0][1] += a.x * b.y; acc[0][2] += a.x * b.z; acc[0][3] += a.x * b.w;
            acc[1][0] += a.y * b.x; acc[1][1] += a.y * b.y; acc[1][2] += a.y * b.z; acc[1][3] += a.y * b.w;
            acc[2][0] += a.z * b.x; acc[2][1] += a.z * b.y; acc[2][2] += a.z * b.z; acc[2][3] += a.z * b.w;
            acc[3][0] += a.w * b.x; acc[3][1] += a.w * b.y; acc[3][2] += a.w * b.z; acc[3][3] += a.w * b.w;
        }
        __syncthreads();
    }
#pragma unroll
    for (int i = 0; i < 4; ++i) {
        int m = bm + ty * 4 + i;
#pragma unroll
        for (int j = 0; j < 4; ++j) {
            int n = bn + tx * 4 + j;
            float v = acc[i][j] + bias[n];
            if (EPI == 1) v = fmaxf(v, 0.f);
            size_t idx = (size_t)m * N + n;
            if (EPI == 2) v += C[idx];
            C[idx] = v;
        }
    }
}

// ---------------------------------------------------------------------------
// KV prep: per (n,h): KV[m][d] = sum_s (elu(K[n,s,h,d])+1) * V[n,s,h,m]
//          Ksum[d]   = sum_s (elu(K[n,s,h,d])+1)
// ---------------------------------------------------------------------------
__global__ __launch_bounds__(256) void kv_prep(const float* __restrict__ Kb,
                                               const float* __restrict__ Vb,
                                               float* __restrict__ KV,
                                               float* __restrict__ Ksum) {
    __shared__ float Ks[16][32];
    __shared__ float Vs[16][32];
    int nh = blockIdx.x;          // 0..63
    int n = nh >> 3, h = nh & 7;
    int tid = threadIdx.x;
    int d = tid & 31, mg = tid >> 5;   // mg 0..7
    float acc0 = 0.f, acc1 = 0.f, acc2 = 0.f, acc3 = 0.f, ksum = 0.f;
    size_t base = ((size_t)n * 4096) * 256 + h * 32;
    for (int s0 = 0; s0 < 4096; s0 += 16) {
#pragma unroll
        for (int r = 0; r < 2; ++r) {
            int ii = tid + r * 256;
            int ss = ii >> 5, ch = ii & 31;
            float kraw = Kb[base + (size_t)(s0 + ss) * 256 + ch];
            Ks[ss][ch] = kraw > 0.f ? kraw + 1.f : expf(kraw);
            Vs[ss][ch] = Vb[base + (size_t)(s0 + ss) * 256 + ch];
        }
        __syncthreads();
#pragma unroll
        for (int ss = 0; ss < 16; ++ss) {
            float kd = Ks[ss][d];
            if (mg == 0) ksum += kd;
            acc0 += kd * Vs[ss][mg * 4 + 0];
            acc1 += kd * Vs[ss][mg * 4 + 1];
            acc2 += kd * Vs[ss][mg * 4 + 2];
            acc3 += kd * Vs[ss][mg * 4 + 3];
        }
        __syncthreads();
    }
    size_t kvbase = (size_t)nh * 1024;
    KV[kvbase + (mg * 4 + 0) * 32 + d] = acc0;
    KV[kvbase + (mg * 4 + 1) * 32 + d] = acc1;
    KV[kvbase + (mg * 4 + 2) * 32 + d] = acc2;
    KV[kvbase + (mg * 4 + 3) * 32 + d] = acc3;
    if (mg == 0) Ksum[nh * 32 + d] = ksum;
}

// ---------------------------------------------------------------------------
// Attention apply: out[n,l,h,m] = (Qp . KV[h,m,:]) / (Qp . Ksum + eps)
// block: 8 tokens of one batch n; loops over heads.
// ---------------------------------------------------------------------------
__global__ __launch_bounds__(256) void attn_apply(const float* __restrict__ Qb,
                                                  const float* __restrict__ KV,
                                                  const float* __restrict__ Ksum,
                                                  float* __restrict__ B) {
    __shared__ float KVs[32][33];
    __shared__ float ks[32];
    __shared__ float qs[8][32];
    int bx = blockIdx.x;
    int n = bx >> 9;                 // 512 blocks per batch
    int tok0 = (bx & 511) << 3;
    int tid = threadIdx.x;
    int tl = tid >> 5, m = tid & 31;
    for (int h = 0; h < 8; ++h) {
        {
            int idx = tid * 4;
            float4 vv = *(const float4*)(KV + (size_t)(n * 8 + h) * 1024 + idx);
            int r = idx >> 5, c = idx & 31;
            KVs[r][c + 0] = vv.x; KVs[r][c + 1] = vv.y;
            KVs[r][c + 2] = vv.z; KVs[r][c + 3] = vv.w;
        }
        if (tid < 32) ks[tid] = Ksum[(n * 8 + h) * 32 + tid];
        {
            float qraw = Qb[((size_t)(n * 4096 + tok0 + tl)) * 256 + h * 32 + m];
            qs[tl][m] = qraw > 0.f ? qraw + 1.f : expf(qraw);
        }
        __syncthreads();
        float acc = 0.f, zacc = 0.f;
#pragma unroll
        for (int dd = 0; dd < 32; ++dd) {
            float qv = qs[tl][dd];
            acc  += qv * KVs[m][dd];
            zacc += qv * ks[dd];
        }
        float z = 1.f / (zacc + 1e-6f);
        B[((size_t)(n * 4096 + tok0 + tl)) * 256 + h * 32 + m] = acc * z;
        __syncthreads();
    }
}

// ---------------------------------------------------------------------------
// LayerNorm over last dim (256), in place. One wave per row.
// ---------------------------------------------------------------------------
__global__ __launch_bounds__(256) void ln_kernel(float* __restrict__ X,
                                                 const float* __restrict__ g,
                                                 const float* __restrict__ b) {
    int row = blockIdx.x * 4 + (threadIdx.x >> 6);
    int lane = threadIdx.x & 63;
    float4* xr = (float4*)(X + (size_t)row * 256);
    float4 v = xr[lane];
    float s  = v.x + v.y + v.z + v.w;
    float sq = v.x * v.x + v.y * v.y + v.z * v.z + v.w * v.w;
#pragma unroll
    for (int off = 32; off > 0; off >>= 1) {
        s  += __shfl_xor(s,  off);
        sq += __shfl_xor(sq, off);
    }
    float mean = s * (1.f / 256.f);
    float var  = sq * (1.f / 256.f) - mean * mean;
    float rstd = rsqrtf(var + 1e-5f);
    int c = lane * 4;
    float4 o;
    o.x = (v.x - mean) * rstd * g[c + 0] + b[c + 0];
    o.y = (v.y - mean) * rstd * g[c + 1] + b[c + 1];
    o.z = (v.z - mean) * rstd * g[c + 2] + b[c + 2];
    o.w = (v.w - mean) * rstd * g[c + 3] + b[c + 3];
    xr[lane] = o;
}

// ---------------------------------------------------------------------------
// Store: X[b,t,c] f32 -> out[b,c,t] f32
// ---------------------------------------------------------------------------
__global__ __launch_bounds__(1024) void store_kernel(const float* __restrict__ X,
                                                     float* __restrict__ out) {
    __shared__ float tile[32][33];
    int b = blockIdx.z;
    int t0 = blockIdx.x * 32, c0 = blockIdx.y * 32;
    tile[threadIdx.y][threadIdx.x] =
        X[((size_t)b * 4096 + t0 + threadIdx.y) * 256 + c0 + threadIdx.x];
    __syncthreads();
    out[((size_t)b * 256 + c0 + threadIdx.y) * 4096 + t0 + threadIdx.x] =
        tile[threadIdx.x][threadIdx.y];
}

// ---------------------------------------------------------------------------
// Workspace layout (aliased; total = 5*32 MiB + 264 KiB ~= 160.3 MiB):
//   X, P2, Qb, Kb, Vb : SZ f32 each
//   Bb aliases Kb (K dead after kv_prep); Hb aliases Kb..Vb (2*SZ)
//   KV : 65536 f32, Ksum : 2048 f32 after Vb
// ---------------------------------------------------------------------------
extern "C" void kernel_launch(void* const* d_in, const int* in_sizes, int n_in,
                              void* d_out, int out_size, void* d_ws, size_t ws_size,
                              hipStream_t stream) {
    const float* ref  = (const float*)d_in[0];
    const float* srcf = (const float*)d_in[1];
    const float* Wq = (const float*)d_in[2];
    const float* bq = (const float*)d_in[3];
    const float* Wk = (const float*)d_in[4];
    const float* bk = (const float*)d_in[5];
    const float* Wv = (const float*)d_in[6];
    const float* bv = (const float*)d_in[7];
    const float* Wo = (const float*)d_in[8];
    const float* bo = (const float*)d_in[9];
    const float* W1 = (const float*)d_in[10];
    const float* b1 = (const float*)d_in[11];
    const float* W2 = (const float*)d_in[12];
    const float* b2 = (const float*)d_in[13];
    const float* g1 = (const float*)d_in[14];
    const float* be1 = (const float*)d_in[15];
    const float* g2 = (const float*)d_in[16];
    const float* be2 = (const float*)d_in[17];

    float* ws = (float*)d_ws;
    const size_t SZ = (size_t)8 * 4096 * 256;   // 8,388,608 floats
    float* X   = ws;
    float* P2  = X + SZ;
    float* Qb  = P2 + SZ;
    float* Kb  = Qb + SZ;
    float* Vb  = Kb + SZ;
    float* Bb  = Kb;               // alias: K dead after kv_prep
    float* Hb  = Kb;               // alias: FFN hidden spans Kb+Vb (2*SZ)
    float* KVb = Vb + SZ;          // 8*8*32*32 = 65536 floats
    float* Ksb = KVb + 65536;      // 2048 floats

    encode_kernel<<<dim3(128, 8, 8), dim3(32, 32), 0, stream>>>(ref, srcf, X, P2);

    for (int L = 0; L < 4; ++L) {
        const float* src = (L & 1) ? P2 : X;   // self: X, cross: P2 (fixed)
        gemm_epi<0><<<dim3(4, 512), 256, 0, stream>>>(X,   Wq + L * 65536, bq + L * 256, Qb, 256, 256);
        gemm_epi<0><<<dim3(4, 512), 256, 0, stream>>>(src, Wk + L * 65536, bk + L * 256, Kb, 256, 256);
        gemm_epi<0><<<dim3(4, 512), 256, 0, stream>>>(src, Wv + L * 65536, bv + L * 256, Vb, 256, 256);
        kv_prep<<<64, 256, 0, stream>>>(Kb, Vb, KVb, Ksb);
        attn_apply<<<4096, 256, 0, stream>>>(Qb, KVb, Ksb, Bb);
        gemm_epi<2><<<dim3(4, 512), 256, 0, stream>>>(Bb, Wo + L * 65536, bo + L * 256, X, 256, 256);
        ln_kernel<<<8192, 256, 0, stream>>>(X, g1 + L * 256, be1 + L * 256);
        gemm_epi<1><<<dim3(8, 512), 256, 0, stream>>>(X,  W1 + L * 131072, b1 + L * 512, Hb, 512, 256);
        gemm_epi<2><<<dim3(4, 512), 256, 0, stream>>>(Hb, W2 + L * 131072, b2 + L * 256, X, 256, 512);
        ln_kernel<<<8192, 256, 0, stream>>>(X, g2 + L * 256, be2 + L * 256);
    }

    store_kernel<<<dim3(128, 8, 8), dim3(32, 32), 0, stream>>>(X, (float*)d_out);
}

// Round 4
// 1206.161 us; speedup vs baseline: 2.6756x; 2.6756x over previous
//
#include <hip/hip_runtime.h>
#include <hip/hip_bf16.h>

typedef __bf16 bf16;
typedef __attribute__((ext_vector_type(8))) __bf16 bf16x8;
typedef __attribute__((ext_vector_type(4))) float f32x4;

__device__ __forceinline__ bf16 f2bf(float f) { return (bf16)f; }

// ---------------------------------------------------------------------------
// Positional encoding value for channel c, token t (t = h*64 + w)
// ---------------------------------------------------------------------------
__device__ __forceinline__ float pe_val(int c, int t) {
    int h = t >> 6, w = t & 63;
    int i = c >> 2, j = c & 3;
    float div = expf(-0.14391156831212787f * (float)i);
    float arg = ((j < 2) ? (float)w : (float)h) * div;
    return (j & 1) ? cosf(arg) : sinf(arg);
}

// ---------------------------------------------------------------------------
// Encode: feat (4,256,4096) f32 -> X[b,t,c], P2[b',t,c] f32 with PE added.
// ---------------------------------------------------------------------------
__global__ __launch_bounds__(1024) void encode_kernel(const float* __restrict__ ref,
                                                      const float* __restrict__ src,
                                                      float* __restrict__ X,
                                                      float* __restrict__ P2) {
    __shared__ float tile[32][33];
    int n = blockIdx.z >> 1, sel = blockIdx.z & 1;
    const float* f = sel ? src : ref;
    int t = blockIdx.x * 32 + threadIdx.x;
    int c = blockIdx.y * 32 + threadIdx.y;
    float v = f[((size_t)n * 256 + c) * 4096 + t] + pe_val(c, t);
    tile[threadIdx.y][threadIdx.x] = v;
    __syncthreads();
    int tt = blockIdx.x * 32 + threadIdx.y;
    int cc = blockIdx.y * 32 + threadIdx.x;
    float o = tile[threadIdx.x][threadIdx.y];
    int bx = sel ? 4 + n : n;
    int bp = sel ? n : 4 + n;
    X [((size_t)bx * 4096 + tt) * 256 + cc] = o;
    P2[((size_t)bp * 4096 + tt) * 256 + cc] = o;
}

// ---------------------------------------------------------------------------
// Weight transpose+convert: W[K,N] f32 -> Wt[N,K] bf16, all 24 mats, 1 launch
// Wt layout per layer (stride 524288): Wq 0, Wk 65536, Wv 131072, Wo 196608,
// W1 262144 (N=512,K=256), W2 393216 (N=256,K=512)
// ---------------------------------------------------------------------------
__global__ __launch_bounds__(1024) void wt_conv(const float* __restrict__ Wq, const float* __restrict__ Wk,
                                                const float* __restrict__ Wv, const float* __restrict__ Wo,
                                                const float* __restrict__ W1, const float* __restrict__ W2,
                                                bf16* __restrict__ Wt) {
    __shared__ float t[32][33];
    int z = blockIdx.z, L = z / 6, m = z - L * 6;
    const float* src; int K, N, doff;
    if      (m == 0) { src = Wq + L * 65536;  K = 256; N = 256; doff = 0; }
    else if (m == 1) { src = Wk + L * 65536;  K = 256; N = 256; doff = 65536; }
    else if (m == 2) { src = Wv + L * 65536;  K = 256; N = 256; doff = 131072; }
    else if (m == 3) { src = Wo + L * 65536;  K = 256; N = 256; doff = 196608; }
    else if (m == 4) { src = W1 + L * 131072; K = 256; N = 512; doff = 262144; }
    else             { src = W2 + L * 131072; K = 512; N = 256; doff = 393216; }
    int n0 = blockIdx.x * 32, k0 = blockIdx.y * 32;
    if (n0 >= N || k0 >= K) return;
    t[threadIdx.y][threadIdx.x] = src[(size_t)(k0 + threadIdx.y) * N + n0 + threadIdx.x];
    __syncthreads();
    bf16* dst = Wt + (size_t)L * 524288 + doff;
    dst[(size_t)(n0 + threadIdx.y) * K + k0 + threadIdx.x] = f2bf(t[threadIdx.x][threadIdx.y]);
}

// ---------------------------------------------------------------------------
// MFMA GEMM: C[M=32768, N] = epi(A[M,K] @ W[K,N] + bias), W given as Wt[N,K] bf16
// 128x128 tile / block (4 waves, each 64x64 = 4x4 frags of 16x16x32 MFMA), BK=32
// EPI: 0 = none, 1 = relu, 2 = in-place residual (C += result)
// ---------------------------------------------------------------------------
template <int EPI>
__global__ __launch_bounds__(256) void gemm_mfma(const float* __restrict__ A,
                                                 const bf16* __restrict__ Wt,
                                                 const float* __restrict__ bias,
                                                 float* __restrict__ C,
                                                 int N, int K) {
    __shared__ bf16 Als[128][40];   // [m][k], pad 40 for bank spread
    __shared__ bf16 Bls[128][40];   // [n][k]
    int tid = threadIdx.x;
    int wave = tid >> 6, lane = tid & 63;
    int bm = blockIdx.y * 128, bn = blockIdx.x * 128;
    int wm = (wave >> 1) * 64, wn = (wave & 1) * 64;
    int l15 = lane & 15;
    int kgrp = (lane >> 4) * 8;
    int sr = tid >> 1;            // 0..127 staging row
    int sk = (tid & 1) * 16;      // k sub-offset 0/16

    f32x4 acc[4][4] = {};

    for (int k0 = 0; k0 < K; k0 += 32) {
        // stage A (f32 -> bf16)
        const float* ap = A + (size_t)(bm + sr) * K + k0 + sk;
        float4 a0 = *(const float4*)(ap + 0);
        float4 a1 = *(const float4*)(ap + 4);
        float4 a2 = *(const float4*)(ap + 8);
        float4 a3 = *(const float4*)(ap + 12);
        bf16x8 p0, p1;
        p0[0] = f2bf(a0.x); p0[1] = f2bf(a0.y); p0[2] = f2bf(a0.z); p0[3] = f2bf(a0.w);
        p0[4] = f2bf(a1.x); p0[5] = f2bf(a1.y); p0[6] = f2bf(a1.z); p0[7] = f2bf(a1.w);
        p1[0] = f2bf(a2.x); p1[1] = f2bf(a2.y); p1[2] = f2bf(a2.z); p1[3] = f2bf(a2.w);
        p1[4] = f2bf(a3.x); p1[5] = f2bf(a3.y); p1[6] = f2bf(a3.z); p1[7] = f2bf(a3.w);
        *(bf16x8*)&Als[sr][sk]     = p0;
        *(bf16x8*)&Als[sr][sk + 8] = p1;
        // stage B (bf16 direct)
        const bf16* bp = Wt + (size_t)(bn + sr) * K + k0 + sk;
        uint4 b0 = *(const uint4*)(bp + 0);
        uint4 b1 = *(const uint4*)(bp + 8);
        *(uint4*)&Bls[sr][sk]     = b0;
        *(uint4*)&Bls[sr][sk + 8] = b1;
        __syncthreads();

        bf16x8 af[4], bfr[4];
#pragma unroll
        for (int i = 0; i < 4; ++i)
            af[i] = *(bf16x8*)&Als[wm + i * 16 + l15][kgrp];
#pragma unroll
        for (int j = 0; j < 4; ++j)
            bfr[j] = *(bf16x8*)&Bls[wn + j * 16 + l15][kgrp];
#pragma unroll
        for (int i = 0; i < 4; ++i)
#pragma unroll
            for (int j = 0; j < 4; ++j)
                acc[i][j] = __builtin_amdgcn_mfma_f32_16x16x32_bf16(af[i], bfr[j], acc[i][j], 0, 0, 0);
        __syncthreads();
    }

    int r4 = (lane >> 4) * 4;
#pragma unroll
    for (int i = 0; i < 4; ++i) {
#pragma unroll
        for (int j = 0; j < 4; ++j) {
            int col = bn + wn + j * 16 + l15;
            float bv = bias[col];
#pragma unroll
            for (int r = 0; r < 4; ++r) {
                int row = bm + wm + i * 16 + r4 + r;
                float v = acc[i][j][r] + bv;
                if (EPI == 1) v = fmaxf(v, 0.f);
                size_t idx = (size_t)row * N + col;
                if (EPI == 2) v += C[idx];
                C[idx] = v;
            }
        }
    }
}

// ---------------------------------------------------------------------------
// KV prep (split 16x over s): per (n,h,split): partial KV[m][d], Ksum[d]
// ---------------------------------------------------------------------------
__global__ __launch_bounds__(256) void kv_prep_part(const float* __restrict__ Kb,
                                                    const float* __restrict__ Vb,
                                                    float* __restrict__ Pkv,
                                                    float* __restrict__ Pks) {
    __shared__ float Ks[16][32];
    __shared__ float Vs[16][32];
    int sp = blockIdx.x;          // 0..15
    int nh = blockIdx.y;          // 0..63
    int n = nh >> 3, h = nh & 7;
    int tid = threadIdx.x;
    int d = tid & 31, mg = tid >> 5;
    float acc0 = 0.f, acc1 = 0.f, acc2 = 0.f, acc3 = 0.f, ksum = 0.f;
    size_t base = ((size_t)n * 4096) * 256 + h * 32;
    int s_beg = sp * 256, s_end = s_beg + 256;
    for (int s0 = s_beg; s0 < s_end; s0 += 16) {
#pragma unroll
        for (int r = 0; r < 2; ++r) {
            int ii = tid + r * 256;
            int ss = ii >> 5, ch = ii & 31;
            float kraw = Kb[base + (size_t)(s0 + ss) * 256 + ch];
            Ks[ss][ch] = kraw > 0.f ? kraw + 1.f : expf(kraw);
            Vs[ss][ch] = Vb[base + (size_t)(s0 + ss) * 256 + ch];
        }
        __syncthreads();
#pragma unroll
        for (int ss = 0; ss < 16; ++ss) {
            float kd = Ks[ss][d];
            if (mg == 0) ksum += kd;
            acc0 += kd * Vs[ss][mg * 4 + 0];
            acc1 += kd * Vs[ss][mg * 4 + 1];
            acc2 += kd * Vs[ss][mg * 4 + 2];
            acc3 += kd * Vs[ss][mg * 4 + 3];
        }
        __syncthreads();
    }
    size_t pb = ((size_t)nh * 16 + sp) * 1024;
    Pkv[pb + (mg * 4 + 0) * 32 + d] = acc0;
    Pkv[pb + (mg * 4 + 1) * 32 + d] = acc1;
    Pkv[pb + (mg * 4 + 2) * 32 + d] = acc2;
    Pkv[pb + (mg * 4 + 3) * 32 + d] = acc3;
    if (mg == 0) Pks[((size_t)nh * 16 + sp) * 32 + d] = ksum;
}

__global__ __launch_bounds__(256) void kv_reduce(const float* __restrict__ Pkv,
                                                 const float* __restrict__ Pks,
                                                 float* __restrict__ KV,
                                                 float* __restrict__ Ksum) {
    int nh = blockIdx.x;
    int e = threadIdx.x * 4;
    float4 s = make_float4(0.f, 0.f, 0.f, 0.f);
    for (int sp = 0; sp < 16; ++sp) {
        float4 p = *(const float4*)&Pkv[((size_t)nh * 16 + sp) * 1024 + e];
        s.x += p.x; s.y += p.y; s.z += p.z; s.w += p.w;
    }
    *(float4*)&KV[(size_t)nh * 1024 + e] = s;
    if (threadIdx.x < 32) {
        float ss = 0.f;
        for (int sp = 0; sp < 16; ++sp) ss += Pks[((size_t)nh * 16 + sp) * 32 + threadIdx.x];
        Ksum[nh * 32 + threadIdx.x] = ss;
    }
}

// ---------------------------------------------------------------------------
// Attention apply: out[n,l,h,m] = (Qp . KV[h,m,:]) / (Qp . Ksum + eps)
// ---------------------------------------------------------------------------
__global__ __launch_bounds__(256) void attn_apply(const float* __restrict__ Qb,
                                                  const float* __restrict__ KV,
                                                  const float* __restrict__ Ksum,
                                                  float* __restrict__ B) {
    __shared__ float KVs[32][33];
    __shared__ float ks[32];
    __shared__ float qs[8][32];
    int bx = blockIdx.x;
    int n = bx >> 9;
    int tok0 = (bx & 511) << 3;
    int tid = threadIdx.x;
    int tl = tid >> 5, m = tid & 31;
    for (int h = 0; h < 8; ++h) {
        {
            int idx = tid * 4;
            float4 vv = *(const float4*)(KV + (size_t)(n * 8 + h) * 1024 + idx);
            int r = idx >> 5, c = idx & 31;
            KVs[r][c + 0] = vv.x; KVs[r][c + 1] = vv.y;
            KVs[r][c + 2] = vv.z; KVs[r][c + 3] = vv.w;
        }
        if (tid < 32) ks[tid] = Ksum[(n * 8 + h) * 32 + tid];
        {
            float qraw = Qb[((size_t)(n * 4096 + tok0 + tl)) * 256 + h * 32 + m];
            qs[tl][m] = qraw > 0.f ? qraw + 1.f : expf(qraw);
        }
        __syncthreads();
        float acc = 0.f, zacc = 0.f;
#pragma unroll
        for (int dd = 0; dd < 32; ++dd) {
            float qv = qs[tl][dd];
            acc  += qv * KVs[m][dd];
            zacc += qv * ks[dd];
        }
        float z = 1.f / (zacc + 1e-6f);
        B[((size_t)(n * 4096 + tok0 + tl)) * 256 + h * 32 + m] = acc * z;
        __syncthreads();
    }
}

// ---------------------------------------------------------------------------
// LayerNorm over last dim (256), in place. One wave per row.
// ---------------------------------------------------------------------------
__global__ __launch_bounds__(256) void ln_kernel(float* __restrict__ X,
                                                 const float* __restrict__ g,
                                                 const float* __restrict__ b) {
    int row = blockIdx.x * 4 + (threadIdx.x >> 6);
    int lane = threadIdx.x & 63;
    float4* xr = (float4*)(X + (size_t)row * 256);
    float4 v = xr[lane];
    float s  = v.x + v.y + v.z + v.w;
    float sq = v.x * v.x + v.y * v.y + v.z * v.z + v.w * v.w;
#pragma unroll
    for (int off = 32; off > 0; off >>= 1) {
        s  += __shfl_xor(s,  off);
        sq += __shfl_xor(sq, off);
    }
    float mean = s * (1.f / 256.f);
    float var  = sq * (1.f / 256.f) - mean * mean;
    float rstd = rsqrtf(var + 1e-5f);
    int c = lane * 4;
    float4 o;
    o.x = (v.x - mean) * rstd * g[c + 0] + b[c + 0];
    o.y = (v.y - mean) * rstd * g[c + 1] + b[c + 1];
    o.z = (v.z - mean) * rstd * g[c + 2] + b[c + 2];
    o.w = (v.w - mean) * rstd * g[c + 3] + b[c + 3];
    xr[lane] = o;
}

// ---------------------------------------------------------------------------
// Store: X[b,t,c] f32 -> out[b,c,t] f32
// ---------------------------------------------------------------------------
__global__ __launch_bounds__(1024) void store_kernel(const float* __restrict__ X,
                                                     float* __restrict__ out) {
    __shared__ float tile[32][33];
    int b = blockIdx.z;
    int t0 = blockIdx.x * 32, c0 = blockIdx.y * 32;
    tile[threadIdx.y][threadIdx.x] =
        X[((size_t)b * 4096 + t0 + threadIdx.y) * 256 + c0 + threadIdx.x];
    __syncthreads();
    out[((size_t)b * 256 + c0 + threadIdx.y) * 4096 + t0 + threadIdx.x] =
        tile[threadIdx.x][threadIdx.y];
}

// ---------------------------------------------------------------------------
// Workspace (f32 units): X,P2,Qb,Kb,Vb (5*SZ=167.8MB) | KVb 65536 | Ksb 2048 |
// Wt 2,097,152 bf16 (=1,048,576 f32 slots) | Pkv 1,048,576 | Pks 32768
// total ~176 MB. Bb/Hb alias Kb (dead after kv/attn).
// ---------------------------------------------------------------------------
extern "C" void kernel_launch(void* const* d_in, const int* in_sizes, int n_in,
                              void* d_out, int out_size, void* d_ws, size_t ws_size,
                              hipStream_t stream) {
    const float* ref  = (const float*)d_in[0];
    const float* srcf = (const float*)d_in[1];
    const float* Wq = (const float*)d_in[2];
    const float* bq = (const float*)d_in[3];
    const float* Wk = (const float*)d_in[4];
    const float* bk = (const float*)d_in[5];
    const float* Wv = (const float*)d_in[6];
    const float* bv = (const float*)d_in[7];
    const float* Wo = (const float*)d_in[8];
    const float* bo = (const float*)d_in[9];
    const float* W1 = (const float*)d_in[10];
    const float* b1 = (const float*)d_in[11];
    const float* W2 = (const float*)d_in[12];
    const float* b2 = (const float*)d_in[13];
    const float* g1 = (const float*)d_in[14];
    const float* be1 = (const float*)d_in[15];
    const float* g2 = (const float*)d_in[16];
    const float* be2 = (const float*)d_in[17];

    float* ws = (float*)d_ws;
    const size_t SZ = (size_t)8 * 4096 * 256;
    float* X   = ws;
    float* P2  = X + SZ;
    float* Qb  = P2 + SZ;
    float* Kb  = Qb + SZ;
    float* Vb  = Kb + SZ;
    float* Bb  = Kb;               // alias: K dead after kv_prep
    float* Hb  = Kb;               // alias: FFN hidden spans Kb+Vb (2*SZ)
    float* KVb = Vb + SZ;
    float* Ksb = KVb + 65536;
    bf16*  Wt  = (bf16*)(Ksb + 2048);       // 2,097,152 bf16
    float* Pkv = (float*)(Wt + 2097152);    // 1,048,576 f32
    float* Pks = Pkv + 1048576;             // 32768 f32

    wt_conv<<<dim3(16, 16, 24), dim3(32, 32), 0, stream>>>(Wq, Wk, Wv, Wo, W1, W2, Wt);
    encode_kernel<<<dim3(128, 8, 8), dim3(32, 32), 0, stream>>>(ref, srcf, X, P2);

    for (int L = 0; L < 4; ++L) {
        const float* src = (L & 1) ? P2 : X;
        const bf16* WtL = Wt + (size_t)L * 524288;
        gemm_mfma<0><<<dim3(2, 256), 256, 0, stream>>>(X,   WtL + 0,      bq + L * 256, Qb, 256, 256);
        gemm_mfma<0><<<dim3(2, 256), 256, 0, stream>>>(src, WtL + 65536,  bk + L * 256, Kb, 256, 256);
        gemm_mfma<0><<<dim3(2, 256), 256, 0, stream>>>(src, WtL + 131072, bv + L * 256, Vb, 256, 256);
        kv_prep_part<<<dim3(16, 64), 256, 0, stream>>>(Kb, Vb, Pkv, Pks);
        kv_reduce<<<64, 256, 0, stream>>>(Pkv, Pks, KVb, Ksb);
        attn_apply<<<4096, 256, 0, stream>>>(Qb, KVb, Ksb, Bb);
        gemm_mfma<2><<<dim3(2, 256), 256, 0, stream>>>(Bb, WtL + 196608, bo + L * 256, X, 256, 256);
        ln_kernel<<<8192, 256, 0, stream>>>(X, g1 + L * 256, be1 + L * 256);
        gemm_mfma<1><<<dim3(4, 256), 256, 0, stream>>>(X,  WtL + 262144, b1 + L * 512, Hb, 512, 256);
        gemm_mfma<2><<<dim3(2, 256), 256, 0, stream>>>(Hb, WtL + 393216, b2 + L * 256, X, 256, 512);
        ln_kernel<<<8192, 256, 0, stream>>>(X, g2 + L * 256, be2 + L * 256);
    }

    store_kernel<<<dim3(128, 8, 8), dim3(32, 32), 0, stream>>>(X, (float*)d_out);
}

// Round 5
// 1056.378 us; speedup vs baseline: 3.0549x; 1.1418x over previous
//
#include <hip/hip_runtime.h>
#include <hip/hip_bf16.h>

typedef __bf16 bf16;
typedef __attribute__((ext_vector_type(8))) __bf16 bf16x8;
typedef __attribute__((ext_vector_type(4))) float f32x4;

__device__ __forceinline__ bf16 f2bf(float f) { return (bf16)f; }

// ---------------------------------------------------------------------------
// Positional encoding value for channel c, token t (t = h*64 + w)
// ---------------------------------------------------------------------------
__device__ __forceinline__ float pe_val(int c, int t) {
    int h = t >> 6, w = t & 63;
    int i = c >> 2, j = c & 3;
    float div = expf(-0.14391156831212787f * (float)i);
    float arg = ((j < 2) ? (float)w : (float)h) * div;
    return (j & 1) ? cosf(arg) : sinf(arg);
}

// ---------------------------------------------------------------------------
// Encode: feat (4,256,4096) f32 -> X[b,t,c], P2[b',t,c] f32 with PE added.
// ---------------------------------------------------------------------------
__global__ __launch_bounds__(1024) void encode_kernel(const float* __restrict__ ref,
                                                      const float* __restrict__ src,
                                                      float* __restrict__ X,
                                                      float* __restrict__ P2) {
    __shared__ float tile[32][33];
    int n = blockIdx.z >> 1, sel = blockIdx.z & 1;
    const float* f = sel ? src : ref;
    int t = blockIdx.x * 32 + threadIdx.x;
    int c = blockIdx.y * 32 + threadIdx.y;
    float v = f[((size_t)n * 256 + c) * 4096 + t] + pe_val(c, t);
    tile[threadIdx.y][threadIdx.x] = v;
    __syncthreads();
    int tt = blockIdx.x * 32 + threadIdx.y;
    int cc = blockIdx.y * 32 + threadIdx.x;
    float o = tile[threadIdx.x][threadIdx.y];
    int bx = sel ? 4 + n : n;
    int bp = sel ? n : 4 + n;
    X [((size_t)bx * 4096 + tt) * 256 + cc] = o;
    P2[((size_t)bp * 4096 + tt) * 256 + cc] = o;
}

// ---------------------------------------------------------------------------
// Weight transpose+convert: W[K,N] f32 -> Wt[N,K] bf16, all 24 mats, 1 launch
// ---------------------------------------------------------------------------
__global__ __launch_bounds__(1024) void wt_conv(const float* __restrict__ Wq, const float* __restrict__ Wk,
                                                const float* __restrict__ Wv, const float* __restrict__ Wo,
                                                const float* __restrict__ W1, const float* __restrict__ W2,
                                                bf16* __restrict__ Wt) {
    __shared__ float t[32][33];
    int z = blockIdx.z, L = z / 6, m = z - L * 6;
    const float* src; int K, N, doff;
    if      (m == 0) { src = Wq + L * 65536;  K = 256; N = 256; doff = 0; }
    else if (m == 1) { src = Wk + L * 65536;  K = 256; N = 256; doff = 65536; }
    else if (m == 2) { src = Wv + L * 65536;  K = 256; N = 256; doff = 131072; }
    else if (m == 3) { src = Wo + L * 65536;  K = 256; N = 256; doff = 196608; }
    else if (m == 4) { src = W1 + L * 131072; K = 256; N = 512; doff = 262144; }
    else             { src = W2 + L * 131072; K = 512; N = 256; doff = 393216; }
    int n0 = blockIdx.x * 32, k0 = blockIdx.y * 32;
    if (n0 >= N || k0 >= K) return;
    t[threadIdx.y][threadIdx.x] = src[(size_t)(k0 + threadIdx.y) * N + n0 + threadIdx.x];
    __syncthreads();
    bf16* dst = Wt + (size_t)L * 524288 + doff;
    dst[(size_t)(n0 + threadIdx.y) * K + k0 + threadIdx.x] = f2bf(t[threadIdx.x][threadIdx.y]);
}

// ---------------------------------------------------------------------------
// MFMA GEMM: C[M=32768, N] = epi(A[M,K] @ W[K,N] + bias), W given as Wt[N,K] bf16
// 128x128 tile / block, BK=32.  EPI: 0 none, 1 relu, 2 residual (C+=), 3 elu+1
// ---------------------------------------------------------------------------
template <int EPI>
__global__ __launch_bounds__(256) void gemm_mfma(const float* __restrict__ A,
                                                 const bf16* __restrict__ Wt,
                                                 const float* __restrict__ bias,
                                                 float* __restrict__ C,
                                                 int N, int K) {
    __shared__ bf16 Als[128][40];
    __shared__ bf16 Bls[128][40];
    int tid = threadIdx.x;
    int wave = tid >> 6, lane = tid & 63;
    int bm = blockIdx.y * 128, bn = blockIdx.x * 128;
    int wm = (wave >> 1) * 64, wn = (wave & 1) * 64;
    int l15 = lane & 15;
    int kgrp = (lane >> 4) * 8;
    int sr = tid >> 1;
    int sk = (tid & 1) * 16;

    f32x4 acc[4][4] = {};

    for (int k0 = 0; k0 < K; k0 += 32) {
        const float* ap = A + (size_t)(bm + sr) * K + k0 + sk;
        float4 a0 = *(const float4*)(ap + 0);
        float4 a1 = *(const float4*)(ap + 4);
        float4 a2 = *(const float4*)(ap + 8);
        float4 a3 = *(const float4*)(ap + 12);
        bf16x8 p0, p1;
        p0[0] = f2bf(a0.x); p0[1] = f2bf(a0.y); p0[2] = f2bf(a0.z); p0[3] = f2bf(a0.w);
        p0[4] = f2bf(a1.x); p0[5] = f2bf(a1.y); p0[6] = f2bf(a1.z); p0[7] = f2bf(a1.w);
        p1[0] = f2bf(a2.x); p1[1] = f2bf(a2.y); p1[2] = f2bf(a2.z); p1[3] = f2bf(a2.w);
        p1[4] = f2bf(a3.x); p1[5] = f2bf(a3.y); p1[6] = f2bf(a3.z); p1[7] = f2bf(a3.w);
        *(bf16x8*)&Als[sr][sk]     = p0;
        *(bf16x8*)&Als[sr][sk + 8] = p1;
        const bf16* bp = Wt + (size_t)(bn + sr) * K + k0 + sk;
        uint4 b0 = *(const uint4*)(bp + 0);
        uint4 b1 = *(const uint4*)(bp + 8);
        *(uint4*)&Bls[sr][sk]     = b0;
        *(uint4*)&Bls[sr][sk + 8] = b1;
        __syncthreads();

        bf16x8 af[4], bfr[4];
#pragma unroll
        for (int i = 0; i < 4; ++i)
            af[i] = *(bf16x8*)&Als[wm + i * 16 + l15][kgrp];
#pragma unroll
        for (int j = 0; j < 4; ++j)
            bfr[j] = *(bf16x8*)&Bls[wn + j * 16 + l15][kgrp];
#pragma unroll
        for (int i = 0; i < 4; ++i)
#pragma unroll
            for (int j = 0; j < 4; ++j)
                acc[i][j] = __builtin_amdgcn_mfma_f32_16x16x32_bf16(af[i], bfr[j], acc[i][j], 0, 0, 0);
        __syncthreads();
    }

    int r4 = (lane >> 4) * 4;
#pragma unroll
    for (int i = 0; i < 4; ++i) {
#pragma unroll
        for (int j = 0; j < 4; ++j) {
            int col = bn + wn + j * 16 + l15;
            float bv = bias[col];
#pragma unroll
            for (int r = 0; r < 4; ++r) {
                int row = bm + wm + i * 16 + r4 + r;
                float v = acc[i][j][r] + bv;
                if (EPI == 1) v = fmaxf(v, 0.f);
                if (EPI == 3) v = v > 0.f ? v + 1.f : expf(v);
                size_t idx = (size_t)row * N + col;
                if (EPI == 2) v += C[idx];
                C[idx] = v;
            }
        }
    }
}

// ---------------------------------------------------------------------------
// KV prep (split 16x over s): K is already elu+1 transformed by GEMM epilogue.
// ---------------------------------------------------------------------------
__global__ __launch_bounds__(256) void kv_prep_part(const float* __restrict__ Kb,
                                                    const float* __restrict__ Vb,
                                                    float* __restrict__ Pkv,
                                                    float* __restrict__ Pks) {
    __shared__ float Ks[16][32];
    __shared__ float Vs[16][32];
    int sp = blockIdx.x;
    int nh = blockIdx.y;
    int n = nh >> 3, h = nh & 7;
    int tid = threadIdx.x;
    int d = tid & 31, mg = tid >> 5;
    float acc0 = 0.f, acc1 = 0.f, acc2 = 0.f, acc3 = 0.f, ksum = 0.f;
    size_t base = ((size_t)n * 4096) * 256 + h * 32;
    int s_beg = sp * 256, s_end = s_beg + 256;
    for (int s0 = s_beg; s0 < s_end; s0 += 16) {
#pragma unroll
        for (int r = 0; r < 2; ++r) {
            int ii = tid + r * 256;
            int ss = ii >> 5, ch = ii & 31;
            Ks[ss][ch] = Kb[base + (size_t)(s0 + ss) * 256 + ch];
            Vs[ss][ch] = Vb[base + (size_t)(s0 + ss) * 256 + ch];
        }
        __syncthreads();
#pragma unroll
        for (int ss = 0; ss < 16; ++ss) {
            float kd = Ks[ss][d];
            if (mg == 0) ksum += kd;
            acc0 += kd * Vs[ss][mg * 4 + 0];
            acc1 += kd * Vs[ss][mg * 4 + 1];
            acc2 += kd * Vs[ss][mg * 4 + 2];
            acc3 += kd * Vs[ss][mg * 4 + 3];
        }
        __syncthreads();
    }
    size_t pb = ((size_t)nh * 16 + sp) * 1024;
    Pkv[pb + (mg * 4 + 0) * 32 + d] = acc0;
    Pkv[pb + (mg * 4 + 1) * 32 + d] = acc1;
    Pkv[pb + (mg * 4 + 2) * 32 + d] = acc2;
    Pkv[pb + (mg * 4 + 3) * 32 + d] = acc3;
    if (mg == 0) Pks[((size_t)nh * 16 + sp) * 32 + d] = ksum;
}

__global__ __launch_bounds__(256) void kv_reduce(const float* __restrict__ Pkv,
                                                 const float* __restrict__ Pks,
                                                 float* __restrict__ KV,
                                                 float* __restrict__ Ksum) {
    int nh = blockIdx.x;
    int e = threadIdx.x * 4;
    float4 s = make_float4(0.f, 0.f, 0.f, 0.f);
    for (int sp = 0; sp < 16; ++sp) {
        float4 p = *(const float4*)&Pkv[((size_t)nh * 16 + sp) * 1024 + e];
        s.x += p.x; s.y += p.y; s.z += p.z; s.w += p.w;
    }
    *(float4*)&KV[(size_t)nh * 1024 + e] = s;
    if (threadIdx.x < 32) {
        float ss = 0.f;
        for (int sp = 0; sp < 16; ++sp) ss += Pks[((size_t)nh * 16 + sp) * 32 + threadIdx.x];
        Ksum[nh * 32 + threadIdx.x] = ss;
    }
}

// ---------------------------------------------------------------------------
// Attention apply v2: 32 tokens/block, Q tile in LDS (broadcast reads),
// per-thread KV row in registers (L2-hot), 2 barriers total.
// Qb already contains elu(q)+1. out[t, h*32+m] = (Qp . KVrow) * Z[t,h]
// ---------------------------------------------------------------------------
__global__ __launch_bounds__(256) void attn_apply(const float* __restrict__ Qb,
                                                  const float* __restrict__ KV,
                                                  const float* __restrict__ Ksum,
                                                  float* __restrict__ B) {
    __shared__ float Qs[32][260];   // pad 260: bank-spreads Z-phase reads
    __shared__ float Zs[32][8];
    int bx = blockIdx.x;
    int n = bx >> 7;                // 128 blocks per batch
    int tok0 = (bx & 127) << 5;
    int tid = threadIdx.x;

    // stage Q tile (32 x 256), fully coalesced float4
    const float4* qsrc = (const float4*)(Qb + ((size_t)(n * 4096 + tok0)) * 256);
#pragma unroll
    for (int k = 0; k < 8; ++k) {
        int e4 = tid + k * 256;           // float4 index in 32x256
        float4 v = qsrc[e4];
        int t = e4 >> 6, c4 = e4 & 63;
        *(float4*)&Qs[t][c4 * 4] = v;
    }

    // per-thread KV row -> registers (from L2; 128B/lane, coalesced in wave)
    int h = tid >> 5, m = tid & 31;
    float kvr[32];
    const float* kvp = KV + (size_t)(n * 8 + h) * 1024 + m * 32;
#pragma unroll
    for (int c = 0; c < 8; ++c) *(float4*)&kvr[c * 4] = *(const float4*)(kvp + c * 4);
    __syncthreads();

    // Z precompute: 256 threads = 32 t x 8 h
    {
        int tz = tid >> 3, hz = tid & 7;
        const float* ksp = Ksum + n * 256 + hz * 32;
        float z = 0.f;
#pragma unroll
        for (int c = 0; c < 8; ++c) {
            float4 q = *(float4*)&Qs[tz][hz * 32 + c * 4];
            float4 k = *(const float4*)(ksp + c * 4);
            z += q.x * k.x + q.y * k.y + q.z * k.z + q.w * k.w;
        }
        Zs[tz][hz] = 1.f / (z + 1e-6f);
    }
    __syncthreads();

    float* outp = B + ((size_t)(n * 4096 + tok0)) * 256 + tid;
#pragma unroll 2
    for (int t = 0; t < 32; ++t) {
        float acc = 0.f;
#pragma unroll
        for (int c = 0; c < 8; ++c) {
            float4 q = *(float4*)&Qs[t][h * 32 + c * 4];   // broadcast (2 addrs/wave)
            acc += q.x * kvr[c * 4 + 0] + q.y * kvr[c * 4 + 1]
                 + q.z * kvr[c * 4 + 2] + q.w * kvr[c * 4 + 3];
        }
        outp[(size_t)t * 256] = acc * Zs[t][h];
    }
}

// ---------------------------------------------------------------------------
// LayerNorm over last dim (256), in place. One wave per row.
// ---------------------------------------------------------------------------
__global__ __launch_bounds__(256) void ln_kernel(float* __restrict__ X,
                                                 const float* __restrict__ g,
                                                 const float* __restrict__ b) {
    int row = blockIdx.x * 4 + (threadIdx.x >> 6);
    int lane = threadIdx.x & 63;
    float4* xr = (float4*)(X + (size_t)row * 256);
    float4 v = xr[lane];
    float s  = v.x + v.y + v.z + v.w;
    float sq = v.x * v.x + v.y * v.y + v.z * v.z + v.w * v.w;
#pragma unroll
    for (int off = 32; off > 0; off >>= 1) {
        s  += __shfl_xor(s,  off);
        sq += __shfl_xor(sq, off);
    }
    float mean = s * (1.f / 256.f);
    float var  = sq * (1.f / 256.f) - mean * mean;
    float rstd = rsqrtf(var + 1e-5f);
    int c = lane * 4;
    float4 o;
    o.x = (v.x - mean) * rstd * g[c + 0] + b[c + 0];
    o.y = (v.y - mean) * rstd * g[c + 1] + b[c + 1];
    o.z = (v.z - mean) * rstd * g[c + 2] + b[c + 2];
    o.w = (v.w - mean) * rstd * g[c + 3] + b[c + 3];
    xr[lane] = o;
}

// ---------------------------------------------------------------------------
// Store: X[b,t,c] f32 -> out[b,c,t] f32
// ---------------------------------------------------------------------------
__global__ __launch_bounds__(1024) void store_kernel(const float* __restrict__ X,
                                                     float* __restrict__ out) {
    __shared__ float tile[32][33];
    int b = blockIdx.z;
    int t0 = blockIdx.x * 32, c0 = blockIdx.y * 32;
    tile[threadIdx.y][threadIdx.x] =
        X[((size_t)b * 4096 + t0 + threadIdx.y) * 256 + c0 + threadIdx.x];
    __syncthreads();
    out[((size_t)b * 256 + c0 + threadIdx.y) * 4096 + t0 + threadIdx.x] =
        tile[threadIdx.x][threadIdx.y];
}

// ---------------------------------------------------------------------------
extern "C" void kernel_launch(void* const* d_in, const int* in_sizes, int n_in,
                              void* d_out, int out_size, void* d_ws, size_t ws_size,
                              hipStream_t stream) {
    const float* ref  = (const float*)d_in[0];
    const float* srcf = (const float*)d_in[1];
    const float* Wq = (const float*)d_in[2];
    const float* bq = (const float*)d_in[3];
    const float* Wk = (const float*)d_in[4];
    const float* bk = (const float*)d_in[5];
    const float* Wv = (const float*)d_in[6];
    const float* bv = (const float*)d_in[7];
    const float* Wo = (const float*)d_in[8];
    const float* bo = (const float*)d_in[9];
    const float* W1 = (const float*)d_in[10];
    const float* b1 = (const float*)d_in[11];
    const float* W2 = (const float*)d_in[12];
    const float* b2 = (const float*)d_in[13];
    const float* g1 = (const float*)d_in[14];
    const float* be1 = (const float*)d_in[15];
    const float* g2 = (const float*)d_in[16];
    const float* be2 = (const float*)d_in[17];

    float* ws = (float*)d_ws;
    const size_t SZ = (size_t)8 * 4096 * 256;
    float* X   = ws;
    float* P2  = X + SZ;
    float* Qb  = P2 + SZ;
    float* Kb  = Qb + SZ;
    float* Vb  = Kb + SZ;
    float* Bb  = Kb;               // alias: K dead after kv_prep
    float* Hb  = Kb;               // alias: FFN hidden spans Kb+Vb (2*SZ)
    float* KVb = Vb + SZ;
    float* Ksb = KVb + 65536;
    bf16*  Wt  = (bf16*)(Ksb + 2048);
    float* Pkv = (float*)(Wt + 2097152);
    float* Pks = Pkv + 1048576;

    wt_conv<<<dim3(16, 16, 24), dim3(32, 32), 0, stream>>>(Wq, Wk, Wv, Wo, W1, W2, Wt);
    encode_kernel<<<dim3(128, 8, 8), dim3(32, 32), 0, stream>>>(ref, srcf, X, P2);

    for (int L = 0; L < 4; ++L) {
        const float* src = (L & 1) ? P2 : X;
        const bf16* WtL = Wt + (size_t)L * 524288;
        gemm_mfma<3><<<dim3(2, 256), 256, 0, stream>>>(X,   WtL + 0,      bq + L * 256, Qb, 256, 256);
        gemm_mfma<3><<<dim3(2, 256), 256, 0, stream>>>(src, WtL + 65536,  bk + L * 256, Kb, 256, 256);
        gemm_mfma<0><<<dim3(2, 256), 256, 0, stream>>>(src, WtL + 131072, bv + L * 256, Vb, 256, 256);
        kv_prep_part<<<dim3(16, 64), 256, 0, stream>>>(Kb, Vb, Pkv, Pks);
        kv_reduce<<<64, 256, 0, stream>>>(Pkv, Pks, KVb, Ksb);
        attn_apply<<<1024, 256, 0, stream>>>(Qb, KVb, Ksb, Bb);
        gemm_mfma<2><<<dim3(2, 256), 256, 0, stream>>>(Bb, WtL + 196608, bo + L * 256, X, 256, 256);
        ln_kernel<<<8192, 256, 0, stream>>>(X, g1 + L * 256, be1 + L * 256);
        gemm_mfma<1><<<dim3(4, 256), 256, 0, stream>>>(X,  WtL + 262144, b1 + L * 512, Hb, 512, 256);
        gemm_mfma<2><<<dim3(2, 256), 256, 0, stream>>>(Hb, WtL + 393216, b2 + L * 256, X, 256, 512);
        ln_kernel<<<8192, 256, 0, stream>>>(X, g2 + L * 256, be2 + L * 256);
    }

    store_kernel<<<dim3(128, 8, 8), dim3(32, 32), 0, stream>>>(X, (float*)d_out);
}

// Round 6
// 934.879 us; speedup vs baseline: 3.4520x; 1.1300x over previous
//
#include <hip/hip_runtime.h>
#include <hip/hip_bf16.h>

typedef __bf16 bf16;
typedef __attribute__((ext_vector_type(8))) __bf16 bf16x8;
typedef __attribute__((ext_vector_type(4))) __bf16 bf16x4;
typedef __attribute__((ext_vector_type(4))) float f32x4;

__device__ __forceinline__ bf16 f2bf(float f) { return (bf16)f; }

// async global->LDS, 16B per lane. LDS dest must be uniform-base + lane*16.
__device__ __forceinline__ void async_cp16(const void* g, void* l) {
    __builtin_amdgcn_global_load_lds(
        (const __attribute__((address_space(1))) unsigned int*)g,
        (__attribute__((address_space(3))) unsigned int*)l, 16, 0, 0);
}

// ---------------------------------------------------------------------------
// Positional encoding value for channel c, token t (t = h*64 + w)
// ---------------------------------------------------------------------------
__device__ __forceinline__ float pe_val(int c, int t) {
    int h = t >> 6, w = t & 63;
    int i = c >> 2, j = c & 3;
    float div = expf(-0.14391156831212787f * (float)i);
    float arg = ((j < 2) ? (float)w : (float)h) * div;
    return (j & 1) ? cosf(arg) : sinf(arg);
}

// ---------------------------------------------------------------------------
// Encode: feat (4,256,4096) f32 -> X[b,t,c] f32 + Xb bf16, P2b bf16.
// ---------------------------------------------------------------------------
__global__ __launch_bounds__(1024) void encode_kernel(const float* __restrict__ ref,
                                                      const float* __restrict__ src,
                                                      float* __restrict__ X,
                                                      bf16* __restrict__ Xb,
                                                      bf16* __restrict__ P2b) {
    __shared__ float tile[32][33];
    int n = blockIdx.z >> 1, sel = blockIdx.z & 1;
    const float* f = sel ? src : ref;
    int t = blockIdx.x * 32 + threadIdx.x;
    int c = blockIdx.y * 32 + threadIdx.y;
    float v = f[((size_t)n * 256 + c) * 4096 + t] + pe_val(c, t);
    tile[threadIdx.y][threadIdx.x] = v;
    __syncthreads();
    int tt = blockIdx.x * 32 + threadIdx.y;
    int cc = blockIdx.y * 32 + threadIdx.x;
    float o = tile[threadIdx.x][threadIdx.y];
    int bx = sel ? 4 + n : n;
    int bp = sel ? n : 4 + n;
    size_t ix = ((size_t)bx * 4096 + tt) * 256 + cc;
    size_t ip = ((size_t)bp * 4096 + tt) * 256 + cc;
    X[ix]  = o;
    Xb[ix] = f2bf(o);
    P2b[ip] = f2bf(o);
}

// ---------------------------------------------------------------------------
// Weight transpose+convert: W[K,N] f32 -> Wt[N,K] bf16, all 24 mats, 1 launch
// ---------------------------------------------------------------------------
__global__ __launch_bounds__(1024) void wt_conv(const float* __restrict__ Wq, const float* __restrict__ Wk,
                                                const float* __restrict__ Wv, const float* __restrict__ Wo,
                                                const float* __restrict__ W1, const float* __restrict__ W2,
                                                bf16* __restrict__ Wt) {
    __shared__ float t[32][33];
    int z = blockIdx.z, L = z / 6, m = z - L * 6;
    const float* src; int K, N, doff;
    if      (m == 0) { src = Wq + L * 65536;  K = 256; N = 256; doff = 0; }
    else if (m == 1) { src = Wk + L * 65536;  K = 256; N = 256; doff = 65536; }
    else if (m == 2) { src = Wv + L * 65536;  K = 256; N = 256; doff = 131072; }
    else if (m == 3) { src = Wo + L * 65536;  K = 256; N = 256; doff = 196608; }
    else if (m == 4) { src = W1 + L * 131072; K = 256; N = 512; doff = 262144; }
    else             { src = W2 + L * 131072; K = 512; N = 256; doff = 393216; }
    int n0 = blockIdx.x * 32, k0 = blockIdx.y * 32;
    if (n0 >= N || k0 >= K) return;
    t[threadIdx.y][threadIdx.x] = src[(size_t)(k0 + threadIdx.y) * N + n0 + threadIdx.x];
    __syncthreads();
    bf16* dst = Wt + (size_t)L * 524288 + doff;
    dst[(size_t)(n0 + threadIdx.y) * K + k0 + threadIdx.x] = f2bf(t[threadIdx.x][threadIdx.y]);
}

// ---------------------------------------------------------------------------
// MFMA GEMM v2: C[M=32768,N] = epi(A[M,K]bf16 @ Wt[N,K]bf16^T + bias)
// 128x128 tile, BK=64, global_load_lds staging with XOR-swizzled LDS layout.
// EPI: 0 none, 1 relu, 2 residual (C f32 +=), 3 elu+1.  OB: 1 = bf16 out.
// ---------------------------------------------------------------------------
template <int EPI, int OB>
__global__ __launch_bounds__(256) void gemm_mfma(const bf16* __restrict__ A,
                                                 const bf16* __restrict__ Wt,
                                                 const float* __restrict__ bias,
                                                 void* __restrict__ Cv,
                                                 int N, int K) {
    __shared__ bf16 Als[128 * 64];   // [row][64k] unpadded; chunk c holds global chunk c^(row&7)
    __shared__ bf16 Bls[128 * 64];
    int tid = threadIdx.x;
    int wave = tid >> 6, lane = tid & 63;
    int bm = blockIdx.y * 128, bn = blockIdx.x * 128;
    int wm = (wave >> 1) * 64, wn = (wave & 1) * 64;
    int l15 = lane & 15, g = lane >> 4;

    f32x4 acc[4][4] = {};

    for (int k0 = 0; k0 < K; k0 += 64) {
#pragma unroll
        for (int r = 0; r < 4; ++r) {
            int L = r * 256 + tid;          // chunk id 0..1023 (16B chunks)
            int row = L >> 3, cs = L & 7;
            int gc = cs ^ (row & 7);        // which global chunk lands in slot cs
            async_cp16(A  + (size_t)(bm + row) * K + k0 + gc * 8, &Als[L * 8]);
            async_cp16(Wt + (size_t)(bn + row) * K + k0 + gc * 8, &Bls[L * 8]);
        }
        __syncthreads();
#pragma unroll
        for (int ks = 0; ks < 2; ++ks) {
            bf16x8 af[4], bfr[4];
#pragma unroll
            for (int i = 0; i < 4; ++i) {
                int row = wm + i * 16 + l15;
                int c = ks * 4 + g;
                af[i] = *(bf16x8*)&Als[row * 64 + ((c ^ (row & 7)) * 8)];
            }
#pragma unroll
            for (int j = 0; j < 4; ++j) {
                int row = wn + j * 16 + l15;
                int c = ks * 4 + g;
                bfr[j] = *(bf16x8*)&Bls[row * 64 + ((c ^ (row & 7)) * 8)];
            }
#pragma unroll
            for (int i = 0; i < 4; ++i)
#pragma unroll
                for (int j = 0; j < 4; ++j)
                    acc[i][j] = __builtin_amdgcn_mfma_f32_16x16x32_bf16(af[i], bfr[j], acc[i][j], 0, 0, 0);
        }
        __syncthreads();
    }

    int r4 = (lane >> 4) * 4;
    float* Cf = (float*)Cv;
    bf16*  Cb = (bf16*)Cv;
#pragma unroll
    for (int i = 0; i < 4; ++i) {
#pragma unroll
        for (int j = 0; j < 4; ++j) {
            int col = bn + wn + j * 16 + l15;
            float bv = bias[col];
#pragma unroll
            for (int r = 0; r < 4; ++r) {
                int row = bm + wm + i * 16 + r4 + r;
                float v = acc[i][j][r] + bv;
                if (EPI == 1) v = fmaxf(v, 0.f);
                if (EPI == 3) v = v > 0.f ? v + 1.f : expf(v);
                size_t idx = (size_t)row * N + col;
                if (EPI == 2) v += Cf[idx];
                if (OB) Cb[idx] = f2bf(v);
                else    Cf[idx] = v;
            }
        }
    }
}

// ---------------------------------------------------------------------------
// KV prep (split 16x over s): K already elu+1. bf16 inputs.
// ---------------------------------------------------------------------------
__global__ __launch_bounds__(256) void kv_prep_part(const bf16* __restrict__ Kb,
                                                    const bf16* __restrict__ Vb,
                                                    float* __restrict__ Pkv,
                                                    float* __restrict__ Pks) {
    __shared__ float Ks[16][32];
    __shared__ float Vs[16][32];
    int sp = blockIdx.x;
    int nh = blockIdx.y;
    int n = nh >> 3, h = nh & 7;
    int tid = threadIdx.x;
    int d = tid & 31, mg = tid >> 5;
    float acc0 = 0.f, acc1 = 0.f, acc2 = 0.f, acc3 = 0.f, ksum = 0.f;
    size_t base = ((size_t)n * 4096) * 256 + h * 32;
    int s_beg = sp * 256, s_end = s_beg + 256;
    for (int s0 = s_beg; s0 < s_end; s0 += 16) {
#pragma unroll
        for (int r = 0; r < 2; ++r) {
            int ii = tid + r * 256;
            int ss = ii >> 5, ch = ii & 31;
            Ks[ss][ch] = (float)Kb[base + (size_t)(s0 + ss) * 256 + ch];
            Vs[ss][ch] = (float)Vb[base + (size_t)(s0 + ss) * 256 + ch];
        }
        __syncthreads();
#pragma unroll
        for (int ss = 0; ss < 16; ++ss) {
            float kd = Ks[ss][d];
            if (mg == 0) ksum += kd;
            acc0 += kd * Vs[ss][mg * 4 + 0];
            acc1 += kd * Vs[ss][mg * 4 + 1];
            acc2 += kd * Vs[ss][mg * 4 + 2];
            acc3 += kd * Vs[ss][mg * 4 + 3];
        }
        __syncthreads();
    }
    size_t pb = ((size_t)nh * 16 + sp) * 1024;
    Pkv[pb + (mg * 4 + 0) * 32 + d] = acc0;
    Pkv[pb + (mg * 4 + 1) * 32 + d] = acc1;
    Pkv[pb + (mg * 4 + 2) * 32 + d] = acc2;
    Pkv[pb + (mg * 4 + 3) * 32 + d] = acc3;
    if (mg == 0) Pks[((size_t)nh * 16 + sp) * 32 + d] = ksum;
}

__global__ __launch_bounds__(256) void kv_reduce(const float* __restrict__ Pkv,
                                                 const float* __restrict__ Pks,
                                                 float* __restrict__ KV,
                                                 float* __restrict__ Ksum) {
    int nh = blockIdx.x;
    int e = threadIdx.x * 4;
    float4 s = make_float4(0.f, 0.f, 0.f, 0.f);
    for (int sp = 0; sp < 16; ++sp) {
        float4 p = *(const float4*)&Pkv[((size_t)nh * 16 + sp) * 1024 + e];
        s.x += p.x; s.y += p.y; s.z += p.z; s.w += p.w;
    }
    *(float4*)&KV[(size_t)nh * 1024 + e] = s;
    if (threadIdx.x < 32) {
        float ss = 0.f;
        for (int sp = 0; sp < 16; ++sp) ss += Pks[((size_t)nh * 16 + sp) * 32 + threadIdx.x];
        Ksum[nh * 32 + threadIdx.x] = ss;
    }
}

// ---------------------------------------------------------------------------
// Attention apply: 32 tokens/block, Q (bf16) tile -> LDS f32, KV row in regs.
// Writes Bb bf16.
// ---------------------------------------------------------------------------
__global__ __launch_bounds__(256) void attn_apply(const bf16* __restrict__ Qb,
                                                  const float* __restrict__ KV,
                                                  const float* __restrict__ Ksum,
                                                  bf16* __restrict__ B) {
    __shared__ float Qs[32][260];
    __shared__ float Zs[32][8];
    int bx = blockIdx.x;
    int n = bx >> 7;
    int tok0 = (bx & 127) << 5;
    int tid = threadIdx.x;

    const bf16* qsrc = Qb + ((size_t)(n * 4096 + tok0)) * 256;
#pragma unroll
    for (int kk = 0; kk < 4; ++kk) {
        int e8 = tid + kk * 256;          // 16B chunk id in 32x256
        bf16x8 v = *(const bf16x8*)(qsrc + (size_t)e8 * 8);
        int t = e8 >> 5, c8 = e8 & 31;
#pragma unroll
        for (int u = 0; u < 8; ++u) Qs[t][c8 * 8 + u] = (float)v[u];
    }

    int h = tid >> 5, m = tid & 31;
    float kvr[32];
    const float* kvp = KV + (size_t)(n * 8 + h) * 1024 + m * 32;
#pragma unroll
    for (int c = 0; c < 8; ++c) *(float4*)&kvr[c * 4] = *(const float4*)(kvp + c * 4);
    __syncthreads();

    {
        int tz = tid >> 3, hz = tid & 7;
        const float* ksp = Ksum + n * 256 + hz * 32;
        float z = 0.f;
#pragma unroll
        for (int c = 0; c < 8; ++c) {
            float4 q = *(float4*)&Qs[tz][hz * 32 + c * 4];
            float4 k = *(const float4*)(ksp + c * 4);
            z += q.x * k.x + q.y * k.y + q.z * k.z + q.w * k.w;
        }
        Zs[tz][hz] = 1.f / (z + 1e-6f);
    }
    __syncthreads();

    bf16* outp = B + ((size_t)(n * 4096 + tok0)) * 256 + tid;
#pragma unroll 2
    for (int t = 0; t < 32; ++t) {
        float acc = 0.f;
#pragma unroll
        for (int c = 0; c < 8; ++c) {
            float4 q = *(float4*)&Qs[t][h * 32 + c * 4];
            acc += q.x * kvr[c * 4 + 0] + q.y * kvr[c * 4 + 1]
                 + q.z * kvr[c * 4 + 2] + q.w * kvr[c * 4 + 3];
        }
        outp[(size_t)t * 256] = f2bf(acc * Zs[t][h]);
    }
}

// ---------------------------------------------------------------------------
// LayerNorm over last dim (256), in place on f32 X; also writes bf16 Xb.
// ---------------------------------------------------------------------------
__global__ __launch_bounds__(256) void ln_kernel(float* __restrict__ X,
                                                 bf16* __restrict__ Xb,
                                                 const float* __restrict__ g,
                                                 const float* __restrict__ b) {
    int row = blockIdx.x * 4 + (threadIdx.x >> 6);
    int lane = threadIdx.x & 63;
    float4* xr = (float4*)(X + (size_t)row * 256);
    float4 v = xr[lane];
    float s  = v.x + v.y + v.z + v.w;
    float sq = v.x * v.x + v.y * v.y + v.z * v.z + v.w * v.w;
#pragma unroll
    for (int off = 32; off > 0; off >>= 1) {
        s  += __shfl_xor(s,  off);
        sq += __shfl_xor(sq, off);
    }
    float mean = s * (1.f / 256.f);
    float var  = sq * (1.f / 256.f) - mean * mean;
    float rstd = rsqrtf(var + 1e-5f);
    int c = lane * 4;
    float4 o;
    o.x = (v.x - mean) * rstd * g[c + 0] + b[c + 0];
    o.y = (v.y - mean) * rstd * g[c + 1] + b[c + 1];
    o.z = (v.z - mean) * rstd * g[c + 2] + b[c + 2];
    o.w = (v.w - mean) * rstd * g[c + 3] + b[c + 3];
    xr[lane] = o;
    bf16x4 ob; ob[0] = f2bf(o.x); ob[1] = f2bf(o.y); ob[2] = f2bf(o.z); ob[3] = f2bf(o.w);
    *(bf16x4*)(Xb + (size_t)row * 256 + c) = ob;
}

// ---------------------------------------------------------------------------
// Store: X[b,t,c] f32 -> out[b,c,t] f32
// ---------------------------------------------------------------------------
__global__ __launch_bounds__(1024) void store_kernel(const float* __restrict__ X,
                                                     float* __restrict__ out) {
    __shared__ float tile[32][33];
    int b = blockIdx.z;
    int t0 = blockIdx.x * 32, c0 = blockIdx.y * 32;
    tile[threadIdx.y][threadIdx.x] =
        X[((size_t)b * 4096 + t0 + threadIdx.y) * 256 + c0 + threadIdx.x];
    __syncthreads();
    out[((size_t)b * 256 + c0 + threadIdx.y) * 4096 + t0 + threadIdx.x] =
        tile[threadIdx.x][threadIdx.y];
}

// ---------------------------------------------------------------------------
extern "C" void kernel_launch(void* const* d_in, const int* in_sizes, int n_in,
                              void* d_out, int out_size, void* d_ws, size_t ws_size,
                              hipStream_t stream) {
    const float* ref  = (const float*)d_in[0];
    const float* srcf = (const float*)d_in[1];
    const float* Wq = (const float*)d_in[2];
    const float* bq = (const float*)d_in[3];
    const float* Wk = (const float*)d_in[4];
    const float* bk = (const float*)d_in[5];
    const float* Wv = (const float*)d_in[6];
    const float* bv = (const float*)d_in[7];
    const float* Wo = (const float*)d_in[8];
    const float* bo = (const float*)d_in[9];
    const float* W1 = (const float*)d_in[10];
    const float* b1 = (const float*)d_in[11];
    const float* W2 = (const float*)d_in[12];
    const float* b2 = (const float*)d_in[13];
    const float* g1 = (const float*)d_in[14];
    const float* be1 = (const float*)d_in[15];
    const float* g2 = (const float*)d_in[16];
    const float* be2 = (const float*)d_in[17];

    const size_t SZ = (size_t)8 * 4096 * 256;
    float* ws  = (float*)d_ws;
    float* X   = ws;                          // SZ f32
    float* KVb = X + SZ;                      // 65536
    float* Ksb = KVb + 65536;                 // 2048
    float* Pkv = Ksb + 2048;                  // 1,048,576
    float* Pks = Pkv + 1048576;               // 32768
    bf16*  Wt  = (bf16*)(Pks + 32768);        // 2,097,152 bf16
    bf16*  Xb  = Wt + 2097152;                // SZ bf16
    bf16*  P2b = Xb + SZ;
    bf16*  Qb  = P2b + SZ;
    bf16*  Kb  = Qb + SZ;
    bf16*  Vb  = Kb + SZ;
    bf16*  Bb  = Kb;                          // alias: K dead after kv_prep
    bf16*  Hb  = Kb;                          // alias: FFN hidden spans Kb+Vb

    wt_conv<<<dim3(16, 16, 24), dim3(32, 32), 0, stream>>>(Wq, Wk, Wv, Wo, W1, W2, Wt);
    encode_kernel<<<dim3(128, 8, 8), dim3(32, 32), 0, stream>>>(ref, srcf, X, Xb, P2b);

    for (int L = 0; L < 4; ++L) {
        const bf16* srcb = (L & 1) ? P2b : Xb;
        const bf16* WtL = Wt + (size_t)L * 524288;
        gemm_mfma<3, 1><<<dim3(2, 256), 256, 0, stream>>>(Xb,   WtL + 0,      bq + L * 256, Qb, 256, 256);
        gemm_mfma<3, 1><<<dim3(2, 256), 256, 0, stream>>>(srcb, WtL + 65536,  bk + L * 256, Kb, 256, 256);
        gemm_mfma<0, 1><<<dim3(2, 256), 256, 0, stream>>>(srcb, WtL + 131072, bv + L * 256, Vb, 256, 256);
        kv_prep_part<<<dim3(16, 64), 256, 0, stream>>>(Kb, Vb, Pkv, Pks);
        kv_reduce<<<64, 256, 0, stream>>>(Pkv, Pks, KVb, Ksb);
        attn_apply<<<1024, 256, 0, stream>>>(Qb, KVb, Ksb, Bb);
        gemm_mfma<2, 0><<<dim3(2, 256), 256, 0, stream>>>(Bb, WtL + 196608, bo + L * 256, X, 256, 256);
        ln_kernel<<<8192, 256, 0, stream>>>(X, Xb, g1 + L * 256, be1 + L * 256);
        gemm_mfma<1, 1><<<dim3(4, 256), 256, 0, stream>>>(Xb, WtL + 262144, b1 + L * 512, Hb, 512, 256);
        gemm_mfma<2, 0><<<dim3(2, 256), 256, 0, stream>>>(Hb, WtL + 393216, b2 + L * 256, X, 256, 512);
        ln_kernel<<<8192, 256, 0, stream>>>(X, Xb, g2 + L * 256, be2 + L * 256);
    }

    store_kernel<<<dim3(128, 8, 8), dim3(32, 32), 0, stream>>>(X, (float*)d_out);
}

// Round 7
// 921.372 us; speedup vs baseline: 3.5026x; 1.0147x over previous
//
#include <hip/hip_runtime.h>
#include <hip/hip_bf16.h>

typedef __bf16 bf16;
typedef __attribute__((ext_vector_type(8))) __bf16 bf16x8;
typedef __attribute__((ext_vector_type(4))) __bf16 bf16x4;
typedef __attribute__((ext_vector_type(4))) float f32x4;

__device__ __forceinline__ bf16 f2bf(float f) { return (bf16)f; }

// async global->LDS, 16B per lane. LDS dest must be uniform-base + lane*16.
__device__ __forceinline__ void async_cp16(const void* g, void* l) {
    __builtin_amdgcn_global_load_lds(
        (const __attribute__((address_space(1))) unsigned int*)g,
        (__attribute__((address_space(3))) unsigned int*)l, 16, 0, 0);
}

// ---------------------------------------------------------------------------
// Positional encoding value for channel c, token t (t = h*64 + w)
// ---------------------------------------------------------------------------
__device__ __forceinline__ float pe_val(int c, int t) {
    int h = t >> 6, w = t & 63;
    int i = c >> 2, j = c & 3;
    float div = expf(-0.14391156831212787f * (float)i);
    float arg = ((j < 2) ? (float)w : (float)h) * div;
    return (j & 1) ? cosf(arg) : sinf(arg);
}

// ---------------------------------------------------------------------------
// Encode: feat (4,256,4096) f32 -> X[b,t,c] f32 + Xb bf16, P2b bf16.
// ---------------------------------------------------------------------------
__global__ __launch_bounds__(1024) void encode_kernel(const float* __restrict__ ref,
                                                      const float* __restrict__ src,
                                                      float* __restrict__ X,
                                                      bf16* __restrict__ Xb,
                                                      bf16* __restrict__ P2b) {
    __shared__ float tile[32][33];
    int n = blockIdx.z >> 1, sel = blockIdx.z & 1;
    const float* f = sel ? src : ref;
    int t = blockIdx.x * 32 + threadIdx.x;
    int c = blockIdx.y * 32 + threadIdx.y;
    float v = f[((size_t)n * 256 + c) * 4096 + t] + pe_val(c, t);
    tile[threadIdx.y][threadIdx.x] = v;
    __syncthreads();
    int tt = blockIdx.x * 32 + threadIdx.y;
    int cc = blockIdx.y * 32 + threadIdx.x;
    float o = tile[threadIdx.x][threadIdx.y];
    int bx = sel ? 4 + n : n;
    int bp = sel ? n : 4 + n;
    size_t ix = ((size_t)bx * 4096 + tt) * 256 + cc;
    size_t ip = ((size_t)bp * 4096 + tt) * 256 + cc;
    X[ix]  = o;
    Xb[ix] = f2bf(o);
    P2b[ip] = f2bf(o);
}

// ---------------------------------------------------------------------------
// Weight transpose+convert: W[K,N] f32 -> Wt[N,K] bf16, all 24 mats, 1 launch
// Per-layer rows: [0,256)=Wq^T [256,512)=Wk^T [512,768)=Wv^T — contiguous QKV.
// ---------------------------------------------------------------------------
__global__ __launch_bounds__(1024) void wt_conv(const float* __restrict__ Wq, const float* __restrict__ Wk,
                                                const float* __restrict__ Wv, const float* __restrict__ Wo,
                                                const float* __restrict__ W1, const float* __restrict__ W2,
                                                bf16* __restrict__ Wt) {
    __shared__ float t[32][33];
    int z = blockIdx.z, L = z / 6, m = z - L * 6;
    const float* src; int K, N, doff;
    if      (m == 0) { src = Wq + L * 65536;  K = 256; N = 256; doff = 0; }
    else if (m == 1) { src = Wk + L * 65536;  K = 256; N = 256; doff = 65536; }
    else if (m == 2) { src = Wv + L * 65536;  K = 256; N = 256; doff = 131072; }
    else if (m == 3) { src = Wo + L * 65536;  K = 256; N = 256; doff = 196608; }
    else if (m == 4) { src = W1 + L * 131072; K = 256; N = 512; doff = 262144; }
    else             { src = W2 + L * 131072; K = 512; N = 256; doff = 393216; }
    int n0 = blockIdx.x * 32, k0 = blockIdx.y * 32;
    if (n0 >= N || k0 >= K) return;
    t[threadIdx.y][threadIdx.x] = src[(size_t)(k0 + threadIdx.y) * N + n0 + threadIdx.x];
    __syncthreads();
    bf16* dst = Wt + (size_t)L * 524288 + doff;
    dst[(size_t)(n0 + threadIdx.y) * K + k0 + threadIdx.x] = f2bf(t[threadIdx.x][threadIdx.y]);
}

// ---------------------------------------------------------------------------
// Fused QKV GEMM: cols [colbase + bn .. ) of [Q|K|V] = A @ Wt^T + bias.
// Per-block segment routing is uniform (128-col tile never crosses 256-col seg).
// Q,K get elu+1 epilogue; V plain. K(dim)=256. Output bf16, stride 256.
// ---------------------------------------------------------------------------
__global__ __launch_bounds__(256) void gemm_qkv(const bf16* __restrict__ A,
                                                const bf16* __restrict__ Wt,
                                                const float* __restrict__ bq,
                                                const float* __restrict__ bk,
                                                const float* __restrict__ bv,
                                                bf16* __restrict__ Q,
                                                bf16* __restrict__ Ko,
                                                bf16* __restrict__ V,
                                                int colbase) {
    __shared__ bf16 Als[128 * 64];
    __shared__ bf16 Bls[128 * 64];
    int tid = threadIdx.x;
    int wave = tid >> 6, lane = tid & 63;
    int bm = blockIdx.y * 128, bn = blockIdx.x * 128;
    int wm = (wave >> 1) * 64, wn = (wave & 1) * 64;
    int l15 = lane & 15, g = lane >> 4;
    const int K = 256;

    int col0 = colbase + bn;
    int seg = col0 >> 8, cloc = col0 & 255;
    const float* bias = seg == 0 ? bq : (seg == 1 ? bk : bv);
    bf16* Out = seg == 0 ? Q : (seg == 1 ? Ko : V);
    bool do_elu = seg < 2;

    f32x4 acc[4][4] = {};

    for (int k0 = 0; k0 < K; k0 += 64) {
#pragma unroll
        for (int r = 0; r < 4; ++r) {
            int Lc = r * 256 + tid;
            int row = Lc >> 3, cs = Lc & 7;
            int gc = cs ^ (row & 7);
            async_cp16(A  + (size_t)(bm + row) * K + k0 + gc * 8, &Als[Lc * 8]);
            async_cp16(Wt + (size_t)(bn + row) * K + k0 + gc * 8, &Bls[Lc * 8]);
        }
        __syncthreads();
#pragma unroll
        for (int ks = 0; ks < 2; ++ks) {
            bf16x8 af[4], bfr[4];
#pragma unroll
            for (int i = 0; i < 4; ++i) {
                int row = wm + i * 16 + l15;
                int c = ks * 4 + g;
                af[i] = *(bf16x8*)&Als[row * 64 + ((c ^ (row & 7)) * 8)];
            }
#pragma unroll
            for (int j = 0; j < 4; ++j) {
                int row = wn + j * 16 + l15;
                int c = ks * 4 + g;
                bfr[j] = *(bf16x8*)&Bls[row * 64 + ((c ^ (row & 7)) * 8)];
            }
#pragma unroll
            for (int i = 0; i < 4; ++i)
#pragma unroll
                for (int j = 0; j < 4; ++j)
                    acc[i][j] = __builtin_amdgcn_mfma_f32_16x16x32_bf16(af[i], bfr[j], acc[i][j], 0, 0, 0);
        }
        __syncthreads();
    }

    int r4 = (lane >> 4) * 4;
#pragma unroll
    for (int i = 0; i < 4; ++i) {
#pragma unroll
        for (int j = 0; j < 4; ++j) {
            int cj = cloc + wn + j * 16 + l15;
            float bvv = bias[cj];
#pragma unroll
            for (int r = 0; r < 4; ++r) {
                int row = bm + wm + i * 16 + r4 + r;
                float v = acc[i][j][r] + bvv;
                if (do_elu) v = v > 0.f ? v + 1.f : expf(v);
                Out[(size_t)row * 256 + cj] = f2bf(v);
            }
        }
    }
}

// ---------------------------------------------------------------------------
// MFMA GEMM: C[M,N] bf16 = epi(A[M,K]bf16 @ Wt[N,K]^T + bias). RELU optional.
// ---------------------------------------------------------------------------
template <int RELU>
__global__ __launch_bounds__(256) void gemm_mfma(const bf16* __restrict__ A,
                                                 const bf16* __restrict__ Wt,
                                                 const float* __restrict__ bias,
                                                 bf16* __restrict__ C,
                                                 int N, int K) {
    __shared__ bf16 Als[128 * 64];
    __shared__ bf16 Bls[128 * 64];
    int tid = threadIdx.x;
    int wave = tid >> 6, lane = tid & 63;
    int bm = blockIdx.y * 128, bn = blockIdx.x * 128;
    int wm = (wave >> 1) * 64, wn = (wave & 1) * 64;
    int l15 = lane & 15, g = lane >> 4;

    f32x4 acc[4][4] = {};

    for (int k0 = 0; k0 < K; k0 += 64) {
#pragma unroll
        for (int r = 0; r < 4; ++r) {
            int Lc = r * 256 + tid;
            int row = Lc >> 3, cs = Lc & 7;
            int gc = cs ^ (row & 7);
            async_cp16(A  + (size_t)(bm + row) * K + k0 + gc * 8, &Als[Lc * 8]);
            async_cp16(Wt + (size_t)(bn + row) * K + k0 + gc * 8, &Bls[Lc * 8]);
        }
        __syncthreads();
#pragma unroll
        for (int ks = 0; ks < 2; ++ks) {
            bf16x8 af[4], bfr[4];
#pragma unroll
            for (int i = 0; i < 4; ++i) {
                int row = wm + i * 16 + l15;
                int c = ks * 4 + g;
                af[i] = *(bf16x8*)&Als[row * 64 + ((c ^ (row & 7)) * 8)];
            }
#pragma unroll
            for (int j = 0; j < 4; ++j) {
                int row = wn + j * 16 + l15;
                int c = ks * 4 + g;
                bfr[j] = *(bf16x8*)&Bls[row * 64 + ((c ^ (row & 7)) * 8)];
            }
#pragma unroll
            for (int i = 0; i < 4; ++i)
#pragma unroll
                for (int j = 0; j < 4; ++j)
                    acc[i][j] = __builtin_amdgcn_mfma_f32_16x16x32_bf16(af[i], bfr[j], acc[i][j], 0, 0, 0);
        }
        __syncthreads();
    }

    int r4 = (lane >> 4) * 4;
#pragma unroll
    for (int i = 0; i < 4; ++i) {
#pragma unroll
        for (int j = 0; j < 4; ++j) {
            int col = bn + wn + j * 16 + l15;
            float bvv = bias[col];
#pragma unroll
            for (int r = 0; r < 4; ++r) {
                int row = bm + wm + i * 16 + r4 + r;
                float v = acc[i][j][r] + bvv;
                if (RELU) v = fmaxf(v, 0.f);
                C[(size_t)row * N + col] = f2bf(v);
            }
        }
    }
}

// ---------------------------------------------------------------------------
// KV prep (split 16x over s): K already elu+1. bf16x8 vector loads, 64-row stages.
// ---------------------------------------------------------------------------
__global__ __launch_bounds__(256) void kv_prep_part(const bf16* __restrict__ Kb,
                                                    const bf16* __restrict__ Vb,
                                                    float* __restrict__ Pkv,
                                                    float* __restrict__ Pks) {
    __shared__ float Ks[64][32];
    __shared__ float Vs[64][32];
    int sp = blockIdx.x;
    int nh = blockIdx.y;
    int n = nh >> 3, h = nh & 7;
    int tid = threadIdx.x;
    int d = tid & 31, mg = tid >> 5;
    int lrow = tid >> 2, lcol = (tid & 3) * 8;
    float acc0 = 0.f, acc1 = 0.f, acc2 = 0.f, acc3 = 0.f, ksum = 0.f;
    size_t base = ((size_t)n * 4096) * 256 + h * 32;
    int s_beg = sp * 256;
#pragma unroll
    for (int st = 0; st < 4; ++st) {
        int s0 = s_beg + st * 64;
        bf16x8 kv8 = *(const bf16x8*)(Kb + base + (size_t)(s0 + lrow) * 256 + lcol);
        bf16x8 vv8 = *(const bf16x8*)(Vb + base + (size_t)(s0 + lrow) * 256 + lcol);
#pragma unroll
        for (int u = 0; u < 8; ++u) { Ks[lrow][lcol + u] = (float)kv8[u]; Vs[lrow][lcol + u] = (float)vv8[u]; }
        __syncthreads();
#pragma unroll
        for (int ss = 0; ss < 64; ++ss) {
            float kd = Ks[ss][d];
            if (mg == 0) ksum += kd;
            acc0 += kd * Vs[ss][mg * 4 + 0];
            acc1 += kd * Vs[ss][mg * 4 + 1];
            acc2 += kd * Vs[ss][mg * 4 + 2];
            acc3 += kd * Vs[ss][mg * 4 + 3];
        }
        __syncthreads();
    }
    size_t pb = ((size_t)nh * 16 + sp) * 1024;
    Pkv[pb + (mg * 4 + 0) * 32 + d] = acc0;
    Pkv[pb + (mg * 4 + 1) * 32 + d] = acc1;
    Pkv[pb + (mg * 4 + 2) * 32 + d] = acc2;
    Pkv[pb + (mg * 4 + 3) * 32 + d] = acc3;
    if (mg == 0) Pks[((size_t)nh * 16 + sp) * 32 + d] = ksum;
}

__global__ __launch_bounds__(256) void kv_reduce(const float* __restrict__ Pkv,
                                                 const float* __restrict__ Pks,
                                                 float* __restrict__ KV,
                                                 float* __restrict__ Ksum) {
    int nh = blockIdx.x;
    int e = threadIdx.x * 4;
    float4 s = make_float4(0.f, 0.f, 0.f, 0.f);
    for (int sp = 0; sp < 16; ++sp) {
        float4 p = *(const float4*)&Pkv[((size_t)nh * 16 + sp) * 1024 + e];
        s.x += p.x; s.y += p.y; s.z += p.z; s.w += p.w;
    }
    *(float4*)&KV[(size_t)nh * 1024 + e] = s;
    if (threadIdx.x < 32) {
        float ss = 0.f;
        for (int sp = 0; sp < 16; ++sp) ss += Pks[((size_t)nh * 16 + sp) * 32 + threadIdx.x];
        Ksum[nh * 32 + threadIdx.x] = ss;
    }
}

// ---------------------------------------------------------------------------
// Attention apply: 32 tokens/block, Q (bf16) tile -> LDS f32, KV row in regs.
// ---------------------------------------------------------------------------
__global__ __launch_bounds__(256) void attn_apply(const bf16* __restrict__ Qb,
                                                  const float* __restrict__ KV,
                                                  const float* __restrict__ Ksum,
                                                  bf16* __restrict__ B) {
    __shared__ float Qs[32][260];
    __shared__ float Zs[32][8];
    int bx = blockIdx.x;
    int n = bx >> 7;
    int tok0 = (bx & 127) << 5;
    int tid = threadIdx.x;

    const bf16* qsrc = Qb + ((size_t)(n * 4096 + tok0)) * 256;
#pragma unroll
    for (int kk = 0; kk < 4; ++kk) {
        int e8 = tid + kk * 256;
        bf16x8 v = *(const bf16x8*)(qsrc + (size_t)e8 * 8);
        int t = e8 >> 5, c8 = e8 & 31;
#pragma unroll
        for (int u = 0; u < 8; ++u) Qs[t][c8 * 8 + u] = (float)v[u];
    }

    int h = tid >> 5, m = tid & 31;
    float kvr[32];
    const float* kvp = KV + (size_t)(n * 8 + h) * 1024 + m * 32;
#pragma unroll
    for (int c = 0; c < 8; ++c) *(float4*)&kvr[c * 4] = *(const float4*)(kvp + c * 4);
    __syncthreads();

    {
        int tz = tid >> 3, hz = tid & 7;
        const float* ksp = Ksum + n * 256 + hz * 32;
        float z = 0.f;
#pragma unroll
        for (int c = 0; c < 8; ++c) {
            float4 q = *(float4*)&Qs[tz][hz * 32 + c * 4];
            float4 k = *(const float4*)(ksp + c * 4);
            z += q.x * k.x + q.y * k.y + q.z * k.z + q.w * k.w;
        }
        Zs[tz][hz] = 1.f / (z + 1e-6f);
    }
    __syncthreads();

    bf16* outp = B + ((size_t)(n * 4096 + tok0)) * 256 + tid;
#pragma unroll 2
    for (int t = 0; t < 32; ++t) {
        float acc = 0.f;
#pragma unroll
        for (int c = 0; c < 8; ++c) {
            float4 q = *(float4*)&Qs[t][h * 32 + c * 4];
            acc += q.x * kvr[c * 4 + 0] + q.y * kvr[c * 4 + 1]
                 + q.z * kvr[c * 4 + 2] + q.w * kvr[c * 4 + 3];
        }
        outp[(size_t)t * 256] = f2bf(acc * Zs[t][h]);
    }
}

// ---------------------------------------------------------------------------
// Residual-add + LayerNorm: y = LN(X + G), X f32 updated, Xb bf16 mirror.
// One wave per row of 256.
// ---------------------------------------------------------------------------
__global__ __launch_bounds__(256) void ln_res(float* __restrict__ X,
                                              bf16* __restrict__ Xb,
                                              const bf16* __restrict__ G,
                                              const float* __restrict__ g,
                                              const float* __restrict__ b) {
    int row = blockIdx.x * 4 + (threadIdx.x >> 6);
    int lane = threadIdx.x & 63;
    float4* xr = (float4*)(X + (size_t)row * 256);
    float4 v = xr[lane];
    bf16x4 gb = *(const bf16x4*)(G + (size_t)row * 256 + lane * 4);
    v.x += (float)gb[0]; v.y += (float)gb[1]; v.z += (float)gb[2]; v.w += (float)gb[3];
    float s  = v.x + v.y + v.z + v.w;
    float sq = v.x * v.x + v.y * v.y + v.z * v.z + v.w * v.w;
#pragma unroll
    for (int off = 32; off > 0; off >>= 1) {
        s  += __shfl_xor(s,  off);
        sq += __shfl_xor(sq, off);
    }
    float mean = s * (1.f / 256.f);
    float var  = sq * (1.f / 256.f) - mean * mean;
    float rstd = rsqrtf(var + 1e-5f);
    int c = lane * 4;
    float4 o;
    o.x = (v.x - mean) * rstd * g[c + 0] + b[c + 0];
    o.y = (v.y - mean) * rstd * g[c + 1] + b[c + 1];
    o.z = (v.z - mean) * rstd * g[c + 2] + b[c + 2];
    o.w = (v.w - mean) * rstd * g[c + 3] + b[c + 3];
    xr[lane] = o;
    bf16x4 ob; ob[0] = f2bf(o.x); ob[1] = f2bf(o.y); ob[2] = f2bf(o.z); ob[3] = f2bf(o.w);
    *(bf16x4*)(Xb + (size_t)row * 256 + c) = ob;
}

// ---------------------------------------------------------------------------
// Store: X[b,t,c] f32 -> out[b,c,t] f32
// ---------------------------------------------------------------------------
__global__ __launch_bounds__(1024) void store_kernel(const float* __restrict__ X,
                                                     float* __restrict__ out) {
    __shared__ float tile[32][33];
    int b = blockIdx.z;
    int t0 = blockIdx.x * 32, c0 = blockIdx.y * 32;
    tile[threadIdx.y][threadIdx.x] =
        X[((size_t)b * 4096 + t0 + threadIdx.y) * 256 + c0 + threadIdx.x];
    __syncthreads();
    out[((size_t)b * 256 + c0 + threadIdx.y) * 4096 + t0 + threadIdx.x] =
        tile[threadIdx.x][threadIdx.y];
}

// ---------------------------------------------------------------------------
extern "C" void kernel_launch(void* const* d_in, const int* in_sizes, int n_in,
                              void* d_out, int out_size, void* d_ws, size_t ws_size,
                              hipStream_t stream) {
    const float* ref  = (const float*)d_in[0];
    const float* srcf = (const float*)d_in[1];
    const float* Wq = (const float*)d_in[2];
    const float* bq = (const float*)d_in[3];
    const float* Wk = (const float*)d_in[4];
    const float* bk = (const float*)d_in[5];
    const float* Wv = (const float*)d_in[6];
    const float* bv = (const float*)d_in[7];
    const float* Wo = (const float*)d_in[8];
    const float* bo = (const float*)d_in[9];
    const float* W1 = (const float*)d_in[10];
    const float* b1 = (const float*)d_in[11];
    const float* W2 = (const float*)d_in[12];
    const float* b2 = (const float*)d_in[13];
    const float* g1 = (const float*)d_in[14];
    const float* be1 = (const float*)d_in[15];
    const float* g2 = (const float*)d_in[16];
    const float* be2 = (const float*)d_in[17];

    const size_t SZ = (size_t)8 * 4096 * 256;
    float* ws  = (float*)d_ws;
    float* X   = ws;                          // SZ f32
    float* KVb = X + SZ;                      // 65536
    float* Ksb = KVb + 65536;                 // 2048
    float* Pkv = Ksb + 2048;                  // 1,048,576
    float* Pks = Pkv + 1048576;               // 32768
    bf16*  Wt  = (bf16*)(Pks + 32768);        // 2,097,152 bf16
    bf16*  Xb  = Wt + 2097152;                // SZ bf16
    bf16*  P2b = Xb + SZ;
    bf16*  Qb  = P2b + SZ;                    // also O-GEMM / FFN2 temp output
    bf16*  Kb  = Qb + SZ;
    bf16*  Vb  = Kb + SZ;
    bf16*  Bb  = Kb;                          // alias: K dead after kv_prep
    bf16*  Hb  = Kb;                          // alias: FFN hidden spans Kb+Vb

    wt_conv<<<dim3(16, 16, 24), dim3(32, 32), 0, stream>>>(Wq, Wk, Wv, Wo, W1, W2, Wt);
    encode_kernel<<<dim3(128, 8, 8), dim3(32, 32), 0, stream>>>(ref, srcf, X, Xb, P2b);

    for (int L = 0; L < 4; ++L) {
        const bf16* WtL = Wt + (size_t)L * 524288;
        const float* bqL = bq + L * 256, *bkL = bk + L * 256, *bvL = bv + L * 256;
        if ((L & 1) == 0) {
            // self: Q,K,V all from Xb — one fused GEMM over 768 cols
            gemm_qkv<<<dim3(6, 256), 256, 0, stream>>>(Xb, WtL, bqL, bkL, bvL, Qb, Kb, Vb, 0);
        } else {
            // cross: Q from Xb; K,V from P2b
            gemm_qkv<<<dim3(2, 256), 256, 0, stream>>>(Xb,  WtL, bqL, bkL, bvL, Qb, Kb, Vb, 0);
            gemm_qkv<<<dim3(4, 256), 256, 0, stream>>>(P2b, WtL + 65536, bqL, bkL, bvL, Qb, Kb, Vb, 256);
        }
        kv_prep_part<<<dim3(16, 64), 256, 0, stream>>>(Kb, Vb, Pkv, Pks);
        kv_reduce<<<64, 256, 0, stream>>>(Pkv, Pks, KVb, Ksb);
        attn_apply<<<1024, 256, 0, stream>>>(Qb, KVb, Ksb, Bb);
        gemm_mfma<0><<<dim3(2, 256), 256, 0, stream>>>(Bb, WtL + 196608, bo + L * 256, Qb, 256, 256);
        ln_res<<<8192, 256, 0, stream>>>(X, Xb, Qb, g1 + L * 256, be1 + L * 256);
        gemm_mfma<1><<<dim3(4, 256), 256, 0, stream>>>(Xb, WtL + 262144, b1 + L * 512, Hb, 512, 256);
        gemm_mfma<0><<<dim3(2, 256), 256, 0, stream>>>(Hb, WtL + 393216, b2 + L * 256, Qb, 256, 512);
        ln_res<<<8192, 256, 0, stream>>>(X, Xb, Qb, g2 + L * 256, be2 + L * 256);
    }

    store_kernel<<<dim3(128, 8, 8), dim3(32, 32), 0, stream>>>(X, (float*)d_out);
}

// Round 8
// 784.482 us; speedup vs baseline: 4.1138x; 1.1745x over previous
//
#include <hip/hip_runtime.h>
#include <hip/hip_bf16.h>

typedef __bf16 bf16;
typedef __attribute__((ext_vector_type(8))) __bf16 bf16x8;
typedef __attribute__((ext_vector_type(4))) __bf16 bf16x4;
typedef __attribute__((ext_vector_type(4))) float f32x4;

__device__ __forceinline__ bf16 f2bf(float f) { return (bf16)f; }

// async global->LDS, 16B per lane. LDS dest must be uniform-base + lane*16.
__device__ __forceinline__ void async_cp16(const void* g, void* l) {
    __builtin_amdgcn_global_load_lds(
        (const __attribute__((address_space(1))) unsigned int*)g,
        (__attribute__((address_space(3))) unsigned int*)l, 16, 0, 0);
}

// ---------------------------------------------------------------------------
// Positional encoding value for channel c, token t (t = h*64 + w)
// ---------------------------------------------------------------------------
__device__ __forceinline__ float pe_val(int c, int t) {
    int h = t >> 6, w = t & 63;
    int i = c >> 2, j = c & 3;
    float div = expf(-0.14391156831212787f * (float)i);
    float arg = ((j < 2) ? (float)w : (float)h) * div;
    return (j & 1) ? cosf(arg) : sinf(arg);
}

// ---------------------------------------------------------------------------
// Encode: feat (4,256,4096) f32 -> X[b,t,c] f32 + Xb bf16, P2b bf16.
// ---------------------------------------------------------------------------
__global__ __launch_bounds__(1024) void encode_kernel(const float* __restrict__ ref,
                                                      const float* __restrict__ src,
                                                      float* __restrict__ X,
                                                      bf16* __restrict__ Xb,
                                                      bf16* __restrict__ P2b) {
    __shared__ float tile[32][33];
    int n = blockIdx.z >> 1, sel = blockIdx.z & 1;
    const float* f = sel ? src : ref;
    int t = blockIdx.x * 32 + threadIdx.x;
    int c = blockIdx.y * 32 + threadIdx.y;
    float v = f[((size_t)n * 256 + c) * 4096 + t] + pe_val(c, t);
    tile[threadIdx.y][threadIdx.x] = v;
    __syncthreads();
    int tt = blockIdx.x * 32 + threadIdx.y;
    int cc = blockIdx.y * 32 + threadIdx.x;
    float o = tile[threadIdx.x][threadIdx.y];
    int bx = sel ? 4 + n : n;
    int bp = sel ? n : 4 + n;
    size_t ix = ((size_t)bx * 4096 + tt) * 256 + cc;
    size_t ip = ((size_t)bp * 4096 + tt) * 256 + cc;
    X[ix]  = o;
    Xb[ix] = f2bf(o);
    P2b[ip] = f2bf(o);
}

// ---------------------------------------------------------------------------
// Weight transpose+convert: W[K,N] f32 -> Wt[N,K] bf16, all 24 mats, 1 launch
// Per-layer rows: [0,256)=Wq^T [256,512)=Wk^T [512,768)=Wv^T — contiguous QKV.
// ---------------------------------------------------------------------------
__global__ __launch_bounds__(1024) void wt_conv(const float* __restrict__ Wq, const float* __restrict__ Wk,
                                                const float* __restrict__ Wv, const float* __restrict__ Wo,
                                                const float* __restrict__ W1, const float* __restrict__ W2,
                                                bf16* __restrict__ Wt) {
    __shared__ float t[32][33];
    int z = blockIdx.z, L = z / 6, m = z - L * 6;
    const float* src; int K, N, doff;
    if      (m == 0) { src = Wq + L * 65536;  K = 256; N = 256; doff = 0; }
    else if (m == 1) { src = Wk + L * 65536;  K = 256; N = 256; doff = 65536; }
    else if (m == 2) { src = Wv + L * 65536;  K = 256; N = 256; doff = 131072; }
    else if (m == 3) { src = Wo + L * 65536;  K = 256; N = 256; doff = 196608; }
    else if (m == 4) { src = W1 + L * 131072; K = 256; N = 512; doff = 262144; }
    else             { src = W2 + L * 131072; K = 512; N = 256; doff = 393216; }
    int n0 = blockIdx.x * 32, k0 = blockIdx.y * 32;
    if (n0 >= N || k0 >= K) return;
    t[threadIdx.y][threadIdx.x] = src[(size_t)(k0 + threadIdx.y) * N + n0 + threadIdx.x];
    __syncthreads();
    bf16* dst = Wt + (size_t)L * 524288 + doff;
    dst[(size_t)(n0 + threadIdx.y) * K + k0 + threadIdx.x] = f2bf(t[threadIdx.x][threadIdx.y]);
}

// ---------------------------------------------------------------------------
// Fused QKV GEMM: cols [colbase + bn .. ) of [Q|K|V] = A @ Wt^T + bias.
// Q,K get elu+1 epilogue; V plain. K(dim)=256. Output bf16, stride 256.
// ---------------------------------------------------------------------------
__global__ __launch_bounds__(256) void gemm_qkv(const bf16* __restrict__ A,
                                                const bf16* __restrict__ Wt,
                                                const float* __restrict__ bq,
                                                const float* __restrict__ bk,
                                                const float* __restrict__ bv,
                                                bf16* __restrict__ Q,
                                                bf16* __restrict__ Ko,
                                                bf16* __restrict__ V,
                                                int colbase) {
    __shared__ bf16 Als[128 * 64];
    __shared__ bf16 Bls[128 * 64];
    int tid = threadIdx.x;
    int wave = tid >> 6, lane = tid & 63;
    int bm = blockIdx.y * 128, bn = blockIdx.x * 128;
    int wm = (wave >> 1) * 64, wn = (wave & 1) * 64;
    int l15 = lane & 15, g = lane >> 4;
    const int K = 256;

    int col0 = colbase + bn;
    int seg = col0 >> 8, cloc = col0 & 255;
    const float* bias = seg == 0 ? bq : (seg == 1 ? bk : bv);
    bf16* Out = seg == 0 ? Q : (seg == 1 ? Ko : V);
    bool do_elu = seg < 2;

    f32x4 acc[4][4] = {};

    for (int k0 = 0; k0 < K; k0 += 64) {
#pragma unroll
        for (int r = 0; r < 4; ++r) {
            int Lc = r * 256 + tid;
            int row = Lc >> 3, cs = Lc & 7;
            int gc = cs ^ (row & 7);
            async_cp16(A  + (size_t)(bm + row) * K + k0 + gc * 8, &Als[Lc * 8]);
            async_cp16(Wt + (size_t)(bn + row) * K + k0 + gc * 8, &Bls[Lc * 8]);
        }
        __syncthreads();
#pragma unroll
        for (int ks = 0; ks < 2; ++ks) {
            bf16x8 af[4], bfr[4];
#pragma unroll
            for (int i = 0; i < 4; ++i) {
                int row = wm + i * 16 + l15;
                int c = ks * 4 + g;
                af[i] = *(bf16x8*)&Als[row * 64 + ((c ^ (row & 7)) * 8)];
            }
#pragma unroll
            for (int j = 0; j < 4; ++j) {
                int row = wn + j * 16 + l15;
                int c = ks * 4 + g;
                bfr[j] = *(bf16x8*)&Bls[row * 64 + ((c ^ (row & 7)) * 8)];
            }
#pragma unroll
            for (int i = 0; i < 4; ++i)
#pragma unroll
                for (int j = 0; j < 4; ++j)
                    acc[i][j] = __builtin_amdgcn_mfma_f32_16x16x32_bf16(af[i], bfr[j], acc[i][j], 0, 0, 0);
        }
        __syncthreads();
    }

    int r4 = (lane >> 4) * 4;
#pragma unroll
    for (int i = 0; i < 4; ++i) {
#pragma unroll
        for (int j = 0; j < 4; ++j) {
            int cj = cloc + wn + j * 16 + l15;
            float bvv = bias[cj];
#pragma unroll
            for (int r = 0; r < 4; ++r) {
                int row = bm + wm + i * 16 + r4 + r;
                float v = acc[i][j][r] + bvv;
                if (do_elu) v = v > 0.f ? v + 1.f : expf(v);
                Out[(size_t)row * 256 + cj] = f2bf(v);
            }
        }
    }
}

// ---------------------------------------------------------------------------
// MFMA GEMM: C[M,N] bf16 = epi(A[M,K]bf16 @ Wt[N,K]^T + bias). RELU optional.
// ---------------------------------------------------------------------------
template <int RELU>
__global__ __launch_bounds__(256) void gemm_mfma(const bf16* __restrict__ A,
                                                 const bf16* __restrict__ Wt,
                                                 const float* __restrict__ bias,
                                                 bf16* __restrict__ C,
                                                 int N, int K) {
    __shared__ bf16 Als[128 * 64];
    __shared__ bf16 Bls[128 * 64];
    int tid = threadIdx.x;
    int wave = tid >> 6, lane = tid & 63;
    int bm = blockIdx.y * 128, bn = blockIdx.x * 128;
    int wm = (wave >> 1) * 64, wn = (wave & 1) * 64;
    int l15 = lane & 15, g = lane >> 4;

    f32x4 acc[4][4] = {};

    for (int k0 = 0; k0 < K; k0 += 64) {
#pragma unroll
        for (int r = 0; r < 4; ++r) {
            int Lc = r * 256 + tid;
            int row = Lc >> 3, cs = Lc & 7;
            int gc = cs ^ (row & 7);
            async_cp16(A  + (size_t)(bm + row) * K + k0 + gc * 8, &Als[Lc * 8]);
            async_cp16(Wt + (size_t)(bn + row) * K + k0 + gc * 8, &Bls[Lc * 8]);
        }
        __syncthreads();
#pragma unroll
        for (int ks = 0; ks < 2; ++ks) {
            bf16x8 af[4], bfr[4];
#pragma unroll
            for (int i = 0; i < 4; ++i) {
                int row = wm + i * 16 + l15;
                int c = ks * 4 + g;
                af[i] = *(bf16x8*)&Als[row * 64 + ((c ^ (row & 7)) * 8)];
            }
#pragma unroll
            for (int j = 0; j < 4; ++j) {
                int row = wn + j * 16 + l15;
                int c = ks * 4 + g;
                bfr[j] = *(bf16x8*)&Bls[row * 64 + ((c ^ (row & 7)) * 8)];
            }
#pragma unroll
            for (int i = 0; i < 4; ++i)
#pragma unroll
                for (int j = 0; j < 4; ++j)
                    acc[i][j] = __builtin_amdgcn_mfma_f32_16x16x32_bf16(af[i], bfr[j], acc[i][j], 0, 0, 0);
        }
        __syncthreads();
    }

    int r4 = (lane >> 4) * 4;
#pragma unroll
    for (int i = 0; i < 4; ++i) {
#pragma unroll
        for (int j = 0; j < 4; ++j) {
            int col = bn + wn + j * 16 + l15;
            float bvv = bias[col];
#pragma unroll
            for (int r = 0; r < 4; ++r) {
                int row = bm + wm + i * 16 + r4 + r;
                float v = acc[i][j][r] + bvv;
                if (RELU) v = fmaxf(v, 0.f);
                C[(size_t)row * N + col] = f2bf(v);
            }
        }
    }
}

// ---------------------------------------------------------------------------
// KV prep v3: grid (32 sp, 64 nh), 256 thr = 4 waves.
// Block stages 128s x 32ch of K,V (f32, 32 KB LDS, one barrier). Wave w reduces
// s in [w*32, w*32+32): each lane owns 4m x 4d = 16 outputs in regs
// (2 ds_read_b128 per s for 20 VALU). Cross-wave reduce reuses staging LDS.
// ---------------------------------------------------------------------------
__global__ __launch_bounds__(256) void kv_prep_part(const bf16* __restrict__ Kb,
                                                    const bf16* __restrict__ Vb,
                                                    float* __restrict__ Pkv,
                                                    float* __restrict__ Pks) {
    __shared__ float Ks[128][32];
    __shared__ float Vs[128][32];
    int sp = blockIdx.x;          // 0..31
    int nh = blockIdx.y;          // 0..63
    int n = nh >> 3, h = nh & 7;
    int tid = threadIdx.x;
    int wave = tid >> 6, lane = tid & 63;
    int mg = lane >> 3;           // 0..7  (4 m each)
    int dg = lane & 7;            // 0..7  (4 d each)
    size_t base = ((size_t)n * 4096 + sp * 128) * 256 + h * 32;

    // stage 128 rows; thread -> (row = p*64 + tid>>2, col8 = (tid&3)*8)
#pragma unroll
    for (int p = 0; p < 2; ++p) {
        int r = p * 64 + (tid >> 2);
        int c = (tid & 3) * 8;
        bf16x8 k8 = *(const bf16x8*)(Kb + base + (size_t)r * 256 + c);
        bf16x8 v8 = *(const bf16x8*)(Vb + base + (size_t)r * 256 + c);
#pragma unroll
        for (int u = 0; u < 8; ++u) { Ks[r][c + u] = (float)k8[u]; Vs[r][c + u] = (float)v8[u]; }
    }
    __syncthreads();

    float acc[4][4] = {};
    float ks4[4] = {};
    int s0 = wave * 32;
    for (int s = s0; s < s0 + 32; ++s) {
        float4 kq = *(float4*)&Ks[s][dg * 4];
        float4 vq = *(float4*)&Vs[s][mg * 4];
        ks4[0] += kq.x; ks4[1] += kq.y; ks4[2] += kq.z; ks4[3] += kq.w;
        acc[0][0] += vq.x * kq.x; acc[0][1] += vq.x * kq.y; acc[0][2] += vq.x * kq.z; acc[0][3] += vq.x * kq.w;
        acc[1][0] += vq.y * kq.x; acc[1][1] += vq.y * kq.y; acc[1][2] += vq.y * kq.z; acc[1][3] += vq.y * kq.w;
        acc[2][0] += vq.z * kq.x; acc[2][1] += vq.z * kq.y; acc[2][2] += vq.z * kq.z; acc[2][3] += vq.z * kq.w;
        acc[3][0] += vq.w * kq.x; acc[3][1] += vq.w * kq.y; acc[3][2] += vq.w * kq.z; acc[3][3] += vq.w * kq.w;
    }
    __syncthreads();

    // cross-wave reduction; reuse Ks (4096 f32) for KV partials, Vs for ksum
    float* R  = &Ks[0][0];
    float* RS = &Vs[0][0];
#pragma unroll
    for (int mi = 0; mi < 4; ++mi)
#pragma unroll
        for (int dj = 0; dj < 4; ++dj)
            R[wave * 1024 + (mg * 4 + mi) * 32 + dg * 4 + dj] = acc[mi][dj];
    if (mg == 0)
#pragma unroll
        for (int dj = 0; dj < 4; ++dj) RS[wave * 32 + dg * 4 + dj] = ks4[dj];
    __syncthreads();

    int e = tid * 4;
    float4 o0 = *(float4*)&R[e];
    float4 o1 = *(float4*)&R[1024 + e];
    float4 o2 = *(float4*)&R[2048 + e];
    float4 o3 = *(float4*)&R[3072 + e];
    float4 o = make_float4(o0.x + o1.x + o2.x + o3.x, o0.y + o1.y + o2.y + o3.y,
                           o0.z + o1.z + o2.z + o3.z, o0.w + o1.w + o2.w + o3.w);
    *(float4*)&Pkv[((size_t)nh * 32 + sp) * 1024 + e] = o;
    if (tid < 32)
        Pks[((size_t)nh * 32 + sp) * 32 + tid] = RS[tid] + RS[32 + tid] + RS[64 + tid] + RS[96 + tid];
}

__global__ __launch_bounds__(256) void kv_reduce(const float* __restrict__ Pkv,
                                                 const float* __restrict__ Pks,
                                                 float* __restrict__ KV,
                                                 float* __restrict__ Ksum) {
    int nh = blockIdx.x;
    int e = threadIdx.x * 4;
    float4 s = make_float4(0.f, 0.f, 0.f, 0.f);
    for (int sp = 0; sp < 32; ++sp) {
        float4 p = *(const float4*)&Pkv[((size_t)nh * 32 + sp) * 1024 + e];
        s.x += p.x; s.y += p.y; s.z += p.z; s.w += p.w;
    }
    *(float4*)&KV[(size_t)nh * 1024 + e] = s;
    if (threadIdx.x < 32) {
        float ss = 0.f;
        for (int sp = 0; sp < 32; ++sp) ss += Pks[((size_t)nh * 32 + sp) * 32 + threadIdx.x];
        Ksum[nh * 32 + threadIdx.x] = ss;
    }
}

// ---------------------------------------------------------------------------
// Attention apply: 32 tokens/block, Q (bf16) tile -> LDS f32, KV row in regs.
// ---------------------------------------------------------------------------
__global__ __launch_bounds__(256) void attn_apply(const bf16* __restrict__ Qb,
                                                  const float* __restrict__ KV,
                                                  const float* __restrict__ Ksum,
                                                  bf16* __restrict__ B) {
    __shared__ float Qs[32][260];
    __shared__ float Zs[32][8];
    int bx = blockIdx.x;
    int n = bx >> 7;
    int tok0 = (bx & 127) << 5;
    int tid = threadIdx.x;

    const bf16* qsrc = Qb + ((size_t)(n * 4096 + tok0)) * 256;
#pragma unroll
    for (int kk = 0; kk < 4; ++kk) {
        int e8 = tid + kk * 256;
        bf16x8 v = *(const bf16x8*)(qsrc + (size_t)e8 * 8);
        int t = e8 >> 5, c8 = e8 & 31;
#pragma unroll
        for (int u = 0; u < 8; ++u) Qs[t][c8 * 8 + u] = (float)v[u];
    }

    int h = tid >> 5, m = tid & 31;
    float kvr[32];
    const float* kvp = KV + (size_t)(n * 8 + h) * 1024 + m * 32;
#pragma unroll
    for (int c = 0; c < 8; ++c) *(float4*)&kvr[c * 4] = *(const float4*)(kvp + c * 4);
    __syncthreads();

    {
        int tz = tid >> 3, hz = tid & 7;
        const float* ksp = Ksum + n * 256 + hz * 32;
        float z = 0.f;
#pragma unroll
        for (int c = 0; c < 8; ++c) {
            float4 q = *(float4*)&Qs[tz][hz * 32 + c * 4];
            float4 k = *(const float4*)(ksp + c * 4);
            z += q.x * k.x + q.y * k.y + q.z * k.z + q.w * k.w;
        }
        Zs[tz][hz] = 1.f / (z + 1e-6f);
    }
    __syncthreads();

    bf16* outp = B + ((size_t)(n * 4096 + tok0)) * 256 + tid;
#pragma unroll 2
    for (int t = 0; t < 32; ++t) {
        float acc = 0.f;
#pragma unroll
        for (int c = 0; c < 8; ++c) {
            float4 q = *(float4*)&Qs[t][h * 32 + c * 4];
            acc += q.x * kvr[c * 4 + 0] + q.y * kvr[c * 4 + 1]
                 + q.z * kvr[c * 4 + 2] + q.w * kvr[c * 4 + 3];
        }
        outp[(size_t)t * 256] = f2bf(acc * Zs[t][h]);
    }
}

// ---------------------------------------------------------------------------
// Residual-add + LayerNorm: y = LN(X + G), X f32 updated, Xb bf16 mirror.
// ---------------------------------------------------------------------------
__global__ __launch_bounds__(256) void ln_res(float* __restrict__ X,
                                              bf16* __restrict__ Xb,
                                              const bf16* __restrict__ G,
                                              const float* __restrict__ g,
                                              const float* __restrict__ b) {
    int row = blockIdx.x * 4 + (threadIdx.x >> 6);
    int lane = threadIdx.x & 63;
    float4* xr = (float4*)(X + (size_t)row * 256);
    float4 v = xr[lane];
    bf16x4 gb = *(const bf16x4*)(G + (size_t)row * 256 + lane * 4);
    v.x += (float)gb[0]; v.y += (float)gb[1]; v.z += (float)gb[2]; v.w += (float)gb[3];
    float s  = v.x + v.y + v.z + v.w;
    float sq = v.x * v.x + v.y * v.y + v.z * v.z + v.w * v.w;
#pragma unroll
    for (int off = 32; off > 0; off >>= 1) {
        s  += __shfl_xor(s,  off);
        sq += __shfl_xor(sq, off);
    }
    float mean = s * (1.f / 256.f);
    float var  = sq * (1.f / 256.f) - mean * mean;
    float rstd = rsqrtf(var + 1e-5f);
    int c = lane * 4;
    float4 o;
    o.x = (v.x - mean) * rstd * g[c + 0] + b[c + 0];
    o.y = (v.y - mean) * rstd * g[c + 1] + b[c + 1];
    o.z = (v.z - mean) * rstd * g[c + 2] + b[c + 2];
    o.w = (v.w - mean) * rstd * g[c + 3] + b[c + 3];
    xr[lane] = o;
    bf16x4 ob; ob[0] = f2bf(o.x); ob[1] = f2bf(o.y); ob[2] = f2bf(o.z); ob[3] = f2bf(o.w);
    *(bf16x4*)(Xb + (size_t)row * 256 + c) = ob;
}

// ---------------------------------------------------------------------------
// Store: X[b,t,c] f32 -> out[b,c,t] f32
// ---------------------------------------------------------------------------
__global__ __launch_bounds__(1024) void store_kernel(const float* __restrict__ X,
                                                     float* __restrict__ out) {
    __shared__ float tile[32][33];
    int b = blockIdx.z;
    int t0 = blockIdx.x * 32, c0 = blockIdx.y * 32;
    tile[threadIdx.y][threadIdx.x] =
        X[((size_t)b * 4096 + t0 + threadIdx.y) * 256 + c0 + threadIdx.x];
    __syncthreads();
    out[((size_t)b * 256 + c0 + threadIdx.y) * 4096 + t0 + threadIdx.x] =
        tile[threadIdx.x][threadIdx.y];
}

// ---------------------------------------------------------------------------
extern "C" void kernel_launch(void* const* d_in, const int* in_sizes, int n_in,
                              void* d_out, int out_size, void* d_ws, size_t ws_size,
                              hipStream_t stream) {
    const float* ref  = (const float*)d_in[0];
    const float* srcf = (const float*)d_in[1];
    const float* Wq = (const float*)d_in[2];
    const float* bq = (const float*)d_in[3];
    const float* Wk = (const float*)d_in[4];
    const float* bk = (const float*)d_in[5];
    const float* Wv = (const float*)d_in[6];
    const float* bv = (const float*)d_in[7];
    const float* Wo = (const float*)d_in[8];
    const float* bo = (const float*)d_in[9];
    const float* W1 = (const float*)d_in[10];
    const float* b1 = (const float*)d_in[11];
    const float* W2 = (const float*)d_in[12];
    const float* b2 = (const float*)d_in[13];
    const float* g1 = (const float*)d_in[14];
    const float* be1 = (const float*)d_in[15];
    const float* g2 = (const float*)d_in[16];
    const float* be2 = (const float*)d_in[17];

    const size_t SZ = (size_t)8 * 4096 * 256;
    float* ws  = (float*)d_ws;
    float* X   = ws;                          // SZ f32
    float* KVb = X + SZ;                      // 65536
    float* Ksb = KVb + 65536;                 // 2048
    float* Pkv = Ksb + 2048;                  // 2,097,152 (64 nh x 32 sp x 1024)
    float* Pks = Pkv + 2097152;               // 65536
    bf16*  Wt  = (bf16*)(Pks + 65536);        // 2,097,152 bf16
    bf16*  Xb  = Wt + 2097152;                // SZ bf16
    bf16*  P2b = Xb + SZ;
    bf16*  Qb  = P2b + SZ;                    // also O-GEMM / FFN2 temp output
    bf16*  Kb  = Qb + SZ;
    bf16*  Vb  = Kb + SZ;
    bf16*  Bb  = Kb;                          // alias: K dead after kv_prep
    bf16*  Hb  = Kb;                          // alias: FFN hidden spans Kb+Vb

    wt_conv<<<dim3(16, 16, 24), dim3(32, 32), 0, stream>>>(Wq, Wk, Wv, Wo, W1, W2, Wt);
    encode_kernel<<<dim3(128, 8, 8), dim3(32, 32), 0, stream>>>(ref, srcf, X, Xb, P2b);

    for (int L = 0; L < 4; ++L) {
        const bf16* WtL = Wt + (size_t)L * 524288;
        const float* bqL = bq + L * 256, *bkL = bk + L * 256, *bvL = bv + L * 256;
        if ((L & 1) == 0) {
            gemm_qkv<<<dim3(6, 256), 256, 0, stream>>>(Xb, WtL, bqL, bkL, bvL, Qb, Kb, Vb, 0);
        } else {
            gemm_qkv<<<dim3(2, 256), 256, 0, stream>>>(Xb,  WtL, bqL, bkL, bvL, Qb, Kb, Vb, 0);
            gemm_qkv<<<dim3(4, 256), 256, 0, stream>>>(P2b, WtL + 65536, bqL, bkL, bvL, Qb, Kb, Vb, 256);
        }
        kv_prep_part<<<dim3(32, 64), 256, 0, stream>>>(Kb, Vb, Pkv, Pks);
        kv_reduce<<<64, 256, 0, stream>>>(Pkv, Pks, KVb, Ksb);
        attn_apply<<<1024, 256, 0, stream>>>(Qb, KVb, Ksb, Bb);
        gemm_mfma<0><<<dim3(2, 256), 256, 0, stream>>>(Bb, WtL + 196608, bo + L * 256, Qb, 256, 256);
        ln_res<<<8192, 256, 0, stream>>>(X, Xb, Qb, g1 + L * 256, be1 + L * 256);
        gemm_mfma<1><<<dim3(4, 256), 256, 0, stream>>>(Xb, WtL + 262144, b1 + L * 512, Hb, 512, 256);
        gemm_mfma<0><<<dim3(2, 256), 256, 0, stream>>>(Hb, WtL + 393216, b2 + L * 256, Qb, 256, 512);
        ln_res<<<8192, 256, 0, stream>>>(X, Xb, Qb, g2 + L * 256, be2 + L * 256);
    }

    store_kernel<<<dim3(128, 8, 8), dim3(32, 32), 0, stream>>>(X, (float*)d_out);
}

// Round 9
// 699.920 us; speedup vs baseline: 4.6108x; 1.1208x over previous
//
#include <hip/hip_runtime.h>
#include <hip/hip_bf16.h>

typedef __bf16 bf16;
typedef __attribute__((ext_vector_type(8))) __bf16 bf16x8;
typedef __attribute__((ext_vector_type(4))) __bf16 bf16x4;
typedef __attribute__((ext_vector_type(4))) float f32x4;

__device__ __forceinline__ bf16 f2bf(float f) { return (bf16)f; }

// async global->LDS, 16B per lane. LDS dest must be uniform-base + lane*16.
__device__ __forceinline__ void async_cp16(const void* g, void* l) {
    __builtin_amdgcn_global_load_lds(
        (const __attribute__((address_space(1))) unsigned int*)g,
        (__attribute__((address_space(3))) unsigned int*)l, 16, 0, 0);
}

// ---------------------------------------------------------------------------
// Positional encoding value for channel c, token t (t = h*64 + w)
// ---------------------------------------------------------------------------
__device__ __forceinline__ float pe_val(int c, int t) {
    int h = t >> 6, w = t & 63;
    int i = c >> 2, j = c & 3;
    float div = expf(-0.14391156831212787f * (float)i);
    float arg = ((j < 2) ? (float)w : (float)h) * div;
    return (j & 1) ? cosf(arg) : sinf(arg);
}

// ---------------------------------------------------------------------------
// Encode: feat (4,256,4096) f32 -> Xb[b,t,c] bf16, P2b bf16 (PE added).
// ---------------------------------------------------------------------------
__global__ __launch_bounds__(1024) void encode_kernel(const float* __restrict__ ref,
                                                      const float* __restrict__ src,
                                                      bf16* __restrict__ Xb,
                                                      bf16* __restrict__ P2b) {
    __shared__ float tile[32][33];
    int n = blockIdx.z >> 1, sel = blockIdx.z & 1;
    const float* f = sel ? src : ref;
    int t = blockIdx.x * 32 + threadIdx.x;
    int c = blockIdx.y * 32 + threadIdx.y;
    float v = f[((size_t)n * 256 + c) * 4096 + t] + pe_val(c, t);
    tile[threadIdx.y][threadIdx.x] = v;
    __syncthreads();
    int tt = blockIdx.x * 32 + threadIdx.y;
    int cc = blockIdx.y * 32 + threadIdx.x;
    float o = tile[threadIdx.x][threadIdx.y];
    int bx = sel ? 4 + n : n;
    int bp = sel ? n : 4 + n;
    Xb [((size_t)bx * 4096 + tt) * 256 + cc] = f2bf(o);
    P2b[((size_t)bp * 4096 + tt) * 256 + cc] = f2bf(o);
}

// ---------------------------------------------------------------------------
// Weight transpose+convert: W[K,N] f32 -> Wt[N,K] bf16, all 24 mats, 1 launch
// Per-layer rows: [0,256)=Wq^T [256,512)=Wk^T [512,768)=Wv^T — contiguous QKV.
// ---------------------------------------------------------------------------
__global__ __launch_bounds__(1024) void wt_conv(const float* __restrict__ Wq, const float* __restrict__ Wk,
                                                const float* __restrict__ Wv, const float* __restrict__ Wo,
                                                const float* __restrict__ W1, const float* __restrict__ W2,
                                                bf16* __restrict__ Wt) {
    __shared__ float t[32][33];
    int z = blockIdx.z, L = z / 6, m = z - L * 6;
    const float* src; int K, N, doff;
    if      (m == 0) { src = Wq + L * 65536;  K = 256; N = 256; doff = 0; }
    else if (m == 1) { src = Wk + L * 65536;  K = 256; N = 256; doff = 65536; }
    else if (m == 2) { src = Wv + L * 65536;  K = 256; N = 256; doff = 131072; }
    else if (m == 3) { src = Wo + L * 65536;  K = 256; N = 256; doff = 196608; }
    else if (m == 4) { src = W1 + L * 131072; K = 256; N = 512; doff = 262144; }
    else             { src = W2 + L * 131072; K = 512; N = 256; doff = 393216; }
    int n0 = blockIdx.x * 32, k0 = blockIdx.y * 32;
    if (n0 >= N || k0 >= K) return;
    t[threadIdx.y][threadIdx.x] = src[(size_t)(k0 + threadIdx.y) * N + n0 + threadIdx.x];
    __syncthreads();
    bf16* dst = Wt + (size_t)L * 524288 + doff;
    dst[(size_t)(n0 + threadIdx.y) * K + k0 + threadIdx.x] = f2bf(t[threadIdx.x][threadIdx.y]);
}

// ---------------------------------------------------------------------------
// Fused QKV GEMM: cols [bn..) of [Q|K|V] = A @ Wt^T + bias, A selected per
// segment: seg0 (Q) <- Aq, seg1/2 (K,V) <- Akv. Self layers: Aq==Akv.
// Q,K get elu+1 epilogue; V plain. K(dim)=256. Output bf16, stride 256.
// ---------------------------------------------------------------------------
__global__ __launch_bounds__(256) void gemm_qkv(const bf16* __restrict__ Aq,
                                                const bf16* __restrict__ Akv,
                                                const bf16* __restrict__ Wt,
                                                const float* __restrict__ bq,
                                                const float* __restrict__ bk,
                                                const float* __restrict__ bv,
                                                bf16* __restrict__ Q,
                                                bf16* __restrict__ Ko,
                                                bf16* __restrict__ V) {
    __shared__ bf16 Als[128 * 64];
    __shared__ bf16 Bls[128 * 64];
    int tid = threadIdx.x;
    int wave = tid >> 6, lane = tid & 63;
    int bm = blockIdx.y * 128, bn = blockIdx.x * 128;
    int wm = (wave >> 1) * 64, wn = (wave & 1) * 64;
    int l15 = lane & 15, g = lane >> 4;
    const int K = 256;

    int seg = bn >> 8, cloc = bn & 255;
    const bf16* A = seg == 0 ? Aq : Akv;
    const float* bias = seg == 0 ? bq : (seg == 1 ? bk : bv);
    bf16* Out = seg == 0 ? Q : (seg == 1 ? Ko : V);
    bool do_elu = seg < 2;

    f32x4 acc[4][4] = {};

    for (int k0 = 0; k0 < K; k0 += 64) {
#pragma unroll
        for (int r = 0; r < 4; ++r) {
            int Lc = r * 256 + tid;
            int row = Lc >> 3, cs = Lc & 7;
            int gc = cs ^ (row & 7);
            async_cp16(A  + (size_t)(bm + row) * K + k0 + gc * 8, &Als[Lc * 8]);
            async_cp16(Wt + (size_t)(bn + row) * K + k0 + gc * 8, &Bls[Lc * 8]);
        }
        __syncthreads();
#pragma unroll
        for (int ks = 0; ks < 2; ++ks) {
            bf16x8 af[4], bfr[4];
#pragma unroll
            for (int i = 0; i < 4; ++i) {
                int row = wm + i * 16 + l15;
                int c = ks * 4 + g;
                af[i] = *(bf16x8*)&Als[row * 64 + ((c ^ (row & 7)) * 8)];
            }
#pragma unroll
            for (int j = 0; j < 4; ++j) {
                int row = wn + j * 16 + l15;
                int c = ks * 4 + g;
                bfr[j] = *(bf16x8*)&Bls[row * 64 + ((c ^ (row & 7)) * 8)];
            }
#pragma unroll
            for (int i = 0; i < 4; ++i)
#pragma unroll
                for (int j = 0; j < 4; ++j)
                    acc[i][j] = __builtin_amdgcn_mfma_f32_16x16x32_bf16(af[i], bfr[j], acc[i][j], 0, 0, 0);
        }
        __syncthreads();
    }

    int r4 = (lane >> 4) * 4;
#pragma unroll
    for (int i = 0; i < 4; ++i) {
#pragma unroll
        for (int j = 0; j < 4; ++j) {
            int cj = cloc + wn + j * 16 + l15;
            float bvv = bias[cj];
#pragma unroll
            for (int r = 0; r < 4; ++r) {
                int row = bm + wm + i * 16 + r4 + r;
                float v = acc[i][j][r] + bvv;
                if (do_elu) v = v > 0.f ? v + 1.f : expf(v);
                Out[(size_t)row * 256 + cj] = f2bf(v);
            }
        }
    }
}

// ---------------------------------------------------------------------------
// MFMA GEMM: C[M,N] bf16 = epi(A[M,K]bf16 @ Wt[N,K]^T + bias). RELU optional.
// ---------------------------------------------------------------------------
template <int RELU>
__global__ __launch_bounds__(256) void gemm_mfma(const bf16* __restrict__ A,
                                                 const bf16* __restrict__ Wt,
                                                 const float* __restrict__ bias,
                                                 bf16* __restrict__ C,
                                                 int N, int K) {
    __shared__ bf16 Als[128 * 64];
    __shared__ bf16 Bls[128 * 64];
    int tid = threadIdx.x;
    int wave = tid >> 6, lane = tid & 63;
    int bm = blockIdx.y * 128, bn = blockIdx.x * 128;
    int wm = (wave >> 1) * 64, wn = (wave & 1) * 64;
    int l15 = lane & 15, g = lane >> 4;

    f32x4 acc[4][4] = {};

    for (int k0 = 0; k0 < K; k0 += 64) {
#pragma unroll
        for (int r = 0; r < 4; ++r) {
            int Lc = r * 256 + tid;
            int row = Lc >> 3, cs = Lc & 7;
            int gc = cs ^ (row & 7);
            async_cp16(A  + (size_t)(bm + row) * K + k0 + gc * 8, &Als[Lc * 8]);
            async_cp16(Wt + (size_t)(bn + row) * K + k0 + gc * 8, &Bls[Lc * 8]);
        }
        __syncthreads();
#pragma unroll
        for (int ks = 0; ks < 2; ++ks) {
            bf16x8 af[4], bfr[4];
#pragma unroll
            for (int i = 0; i < 4; ++i) {
                int row = wm + i * 16 + l15;
                int c = ks * 4 + g;
                af[i] = *(bf16x8*)&Als[row * 64 + ((c ^ (row & 7)) * 8)];
            }
#pragma unroll
            for (int j = 0; j < 4; ++j) {
                int row = wn + j * 16 + l15;
                int c = ks * 4 + g;
                bfr[j] = *(bf16x8*)&Bls[row * 64 + ((c ^ (row & 7)) * 8)];
            }
#pragma unroll
            for (int i = 0; i < 4; ++i)
#pragma unroll
                for (int j = 0; j < 4; ++j)
                    acc[i][j] = __builtin_amdgcn_mfma_f32_16x16x32_bf16(af[i], bfr[j], acc[i][j], 0, 0, 0);
        }
        __syncthreads();
    }

    int r4 = (lane >> 4) * 4;
#pragma unroll
    for (int i = 0; i < 4; ++i) {
#pragma unroll
        for (int j = 0; j < 4; ++j) {
            int col = bn + wn + j * 16 + l15;
            float bvv = bias[col];
#pragma unroll
            for (int r = 0; r < 4; ++r) {
                int row = bm + wm + i * 16 + r4 + r;
                float v = acc[i][j][r] + bvv;
                if (RELU) v = fmaxf(v, 0.f);
                C[(size_t)row * N + col] = f2bf(v);
            }
        }
    }
}

// ---------------------------------------------------------------------------
// KV prep v3: grid (32 sp, 64 nh), 256 thr = 4 waves.
// Block stages 128s x 32ch of K,V (f32, 32 KB LDS, one barrier). Wave w reduces
// s in [w*32, w*32+32): each lane owns 4m x 4d = 16 outputs in regs.
// Cross-wave reduce reuses staging LDS.
// ---------------------------------------------------------------------------
__global__ __launch_bounds__(256) void kv_prep_part(const bf16* __restrict__ Kb,
                                                    const bf16* __restrict__ Vb,
                                                    float* __restrict__ Pkv,
                                                    float* __restrict__ Pks) {
    __shared__ float Ks[128][32];
    __shared__ float Vs[128][32];
    int sp = blockIdx.x;          // 0..31
    int nh = blockIdx.y;          // 0..63
    int n = nh >> 3, h = nh & 7;
    int tid = threadIdx.x;
    int wave = tid >> 6, lane = tid & 63;
    int mg = lane >> 3;           // 0..7  (4 m each)
    int dg = lane & 7;            // 0..7  (4 d each)
    size_t base = ((size_t)n * 4096 + sp * 128) * 256 + h * 32;

#pragma unroll
    for (int p = 0; p < 2; ++p) {
        int r = p * 64 + (tid >> 2);
        int c = (tid & 3) * 8;
        bf16x8 k8 = *(const bf16x8*)(Kb + base + (size_t)r * 256 + c);
        bf16x8 v8 = *(const bf16x8*)(Vb + base + (size_t)r * 256 + c);
#pragma unroll
        for (int u = 0; u < 8; ++u) { Ks[r][c + u] = (float)k8[u]; Vs[r][c + u] = (float)v8[u]; }
    }
    __syncthreads();

    float acc[4][4] = {};
    float ks4[4] = {};
    int s0 = wave * 32;
    for (int s = s0; s < s0 + 32; ++s) {
        float4 kq = *(float4*)&Ks[s][dg * 4];
        float4 vq = *(float4*)&Vs[s][mg * 4];
        ks4[0] += kq.x; ks4[1] += kq.y; ks4[2] += kq.z; ks4[3] += kq.w;
        acc[0][0] += vq.x * kq.x; acc[0][1] += vq.x * kq.y; acc[0][2] += vq.x * kq.z; acc[0][3] += vq.x * kq.w;
        acc[1][0] += vq.y * kq.x; acc[1][1] += vq.y * kq.y; acc[1][2] += vq.y * kq.z; acc[1][3] += vq.y * kq.w;
        acc[2][0] += vq.z * kq.x; acc[2][1] += vq.z * kq.y; acc[2][2] += vq.z * kq.z; acc[2][3] += vq.z * kq.w;
        acc[3][0] += vq.w * kq.x; acc[3][1] += vq.w * kq.y; acc[3][2] += vq.w * kq.z; acc[3][3] += vq.w * kq.w;
    }
    __syncthreads();

    float* R  = &Ks[0][0];
    float* RS = &Vs[0][0];
#pragma unroll
    for (int mi = 0; mi < 4; ++mi)
#pragma unroll
        for (int dj = 0; dj < 4; ++dj)
            R[wave * 1024 + (mg * 4 + mi) * 32 + dg * 4 + dj] = acc[mi][dj];
    if (mg == 0)
#pragma unroll
        for (int dj = 0; dj < 4; ++dj) RS[wave * 32 + dg * 4 + dj] = ks4[dj];
    __syncthreads();

    int e = tid * 4;
    float4 o0 = *(float4*)&R[e];
    float4 o1 = *(float4*)&R[1024 + e];
    float4 o2 = *(float4*)&R[2048 + e];
    float4 o3 = *(float4*)&R[3072 + e];
    float4 o = make_float4(o0.x + o1.x + o2.x + o3.x, o0.y + o1.y + o2.y + o3.y,
                           o0.z + o1.z + o2.z + o3.z, o0.w + o1.w + o2.w + o3.w);
    *(float4*)&Pkv[((size_t)nh * 32 + sp) * 1024 + e] = o;
    if (tid < 32)
        Pks[((size_t)nh * 32 + sp) * 32 + tid] = RS[tid] + RS[32 + tid] + RS[64 + tid] + RS[96 + tid];
}

__global__ __launch_bounds__(256) void kv_reduce(const float* __restrict__ Pkv,
                                                 const float* __restrict__ Pks,
                                                 float* __restrict__ KV,
                                                 float* __restrict__ Ksum) {
    int nh = blockIdx.x;
    int e = threadIdx.x * 4;
    float4 s = make_float4(0.f, 0.f, 0.f, 0.f);
    for (int sp = 0; sp < 32; ++sp) {
        float4 p = *(const float4*)&Pkv[((size_t)nh * 32 + sp) * 1024 + e];
        s.x += p.x; s.y += p.y; s.z += p.z; s.w += p.w;
    }
    *(float4*)&KV[(size_t)nh * 1024 + e] = s;
    if (threadIdx.x < 32) {
        float ss = 0.f;
        for (int sp = 0; sp < 32; ++sp) ss += Pks[((size_t)nh * 32 + sp) * 32 + threadIdx.x];
        Ksum[nh * 32 + threadIdx.x] = ss;
    }
}

// ---------------------------------------------------------------------------
// Attention apply: 32 tokens/block, Q (bf16) tile -> LDS f32, KV row in regs.
// ---------------------------------------------------------------------------
__global__ __launch_bounds__(256) void attn_apply(const bf16* __restrict__ Qb,
                                                  const float* __restrict__ KV,
                                                  const float* __restrict__ Ksum,
                                                  bf16* __restrict__ B) {
    __shared__ float Qs[32][260];
    __shared__ float Zs[32][8];
    int bx = blockIdx.x;
    int n = bx >> 7;
    int tok0 = (bx & 127) << 5;
    int tid = threadIdx.x;

    const bf16* qsrc = Qb + ((size_t)(n * 4096 + tok0)) * 256;
#pragma unroll
    for (int kk = 0; kk < 4; ++kk) {
        int e8 = tid + kk * 256;
        bf16x8 v = *(const bf16x8*)(qsrc + (size_t)e8 * 8);
        int t = e8 >> 5, c8 = e8 & 31;
#pragma unroll
        for (int u = 0; u < 8; ++u) Qs[t][c8 * 8 + u] = (float)v[u];
    }

    int h = tid >> 5, m = tid & 31;
    float kvr[32];
    const float* kvp = KV + (size_t)(n * 8 + h) * 1024 + m * 32;
#pragma unroll
    for (int c = 0; c < 8; ++c) *(float4*)&kvr[c * 4] = *(const float4*)(kvp + c * 4);
    __syncthreads();

    {
        int tz = tid >> 3, hz = tid & 7;
        const float* ksp = Ksum + n * 256 + hz * 32;
        float z = 0.f;
#pragma unroll
        for (int c = 0; c < 8; ++c) {
            float4 q = *(float4*)&Qs[tz][hz * 32 + c * 4];
            float4 k = *(const float4*)(ksp + c * 4);
            z += q.x * k.x + q.y * k.y + q.z * k.z + q.w * k.w;
        }
        Zs[tz][hz] = 1.f / (z + 1e-6f);
    }
    __syncthreads();

    bf16* outp = B + ((size_t)(n * 4096 + tok0)) * 256 + tid;
#pragma unroll 2
    for (int t = 0; t < 32; ++t) {
        float acc = 0.f;
#pragma unroll
        for (int c = 0; c < 8; ++c) {
            float4 q = *(float4*)&Qs[t][h * 32 + c * 4];
            acc += q.x * kvr[c * 4 + 0] + q.y * kvr[c * 4 + 1]
                 + q.z * kvr[c * 4 + 2] + q.w * kvr[c * 4 + 3];
        }
        outp[(size_t)t * 256] = f2bf(acc * Zs[t][h]);
    }
}

// ---------------------------------------------------------------------------
// Residual-add + LayerNorm, bf16 residual stream: Xb = LN(Xb + G) (f32 math).
// One wave per row of 256.
// ---------------------------------------------------------------------------
__global__ __launch_bounds__(256) void ln_res(bf16* __restrict__ Xb,
                                              const bf16* __restrict__ G,
                                              const float* __restrict__ g,
                                              const float* __restrict__ b) {
    int row = blockIdx.x * 4 + (threadIdx.x >> 6);
    int lane = threadIdx.x & 63;
    int c = lane * 4;
    bf16x4 xb = *(const bf16x4*)(Xb + (size_t)row * 256 + c);
    bf16x4 gb = *(const bf16x4*)(G + (size_t)row * 256 + c);
    float4 v;
    v.x = (float)xb[0] + (float)gb[0];
    v.y = (float)xb[1] + (float)gb[1];
    v.z = (float)xb[2] + (float)gb[2];
    v.w = (float)xb[3] + (float)gb[3];
    float s  = v.x + v.y + v.z + v.w;
    float sq = v.x * v.x + v.y * v.y + v.z * v.z + v.w * v.w;
#pragma unroll
    for (int off = 32; off > 0; off >>= 1) {
        s  += __shfl_xor(s,  off);
        sq += __shfl_xor(sq, off);
    }
    float mean = s * (1.f / 256.f);
    float var  = sq * (1.f / 256.f) - mean * mean;
    float rstd = rsqrtf(var + 1e-5f);
    float4 o;
    o.x = (v.x - mean) * rstd * g[c + 0] + b[c + 0];
    o.y = (v.y - mean) * rstd * g[c + 1] + b[c + 1];
    o.z = (v.z - mean) * rstd * g[c + 2] + b[c + 2];
    o.w = (v.w - mean) * rstd * g[c + 3] + b[c + 3];
    bf16x4 ob; ob[0] = f2bf(o.x); ob[1] = f2bf(o.y); ob[2] = f2bf(o.z); ob[3] = f2bf(o.w);
    *(bf16x4*)(Xb + (size_t)row * 256 + c) = ob;
}

// ---------------------------------------------------------------------------
// Store: Xb[b,t,c] bf16 -> out[b,c,t] f32
// ---------------------------------------------------------------------------
__global__ __launch_bounds__(1024) void store_kernel(const bf16* __restrict__ Xb,
                                                     float* __restrict__ out) {
    __shared__ float tile[32][33];
    int b = blockIdx.z;
    int t0 = blockIdx.x * 32, c0 = blockIdx.y * 32;
    tile[threadIdx.y][threadIdx.x] =
        (float)Xb[((size_t)b * 4096 + t0 + threadIdx.y) * 256 + c0 + threadIdx.x];
    __syncthreads();
    out[((size_t)b * 256 + c0 + threadIdx.y) * 4096 + t0 + threadIdx.x] =
        tile[threadIdx.x][threadIdx.y];
}

// ---------------------------------------------------------------------------
extern "C" void kernel_launch(void* const* d_in, const int* in_sizes, int n_in,
                              void* d_out, int out_size, void* d_ws, size_t ws_size,
                              hipStream_t stream) {
    const float* ref  = (const float*)d_in[0];
    const float* srcf = (const float*)d_in[1];
    const float* Wq = (const float*)d_in[2];
    const float* bq = (const float*)d_in[3];
    const float* Wk = (const float*)d_in[4];
    const float* bk = (const float*)d_in[5];
    const float* Wv = (const float*)d_in[6];
    const float* bv = (const float*)d_in[7];
    const float* Wo = (const float*)d_in[8];
    const float* bo = (const float*)d_in[9];
    const float* W1 = (const float*)d_in[10];
    const float* b1 = (const float*)d_in[11];
    const float* W2 = (const float*)d_in[12];
    const float* b2 = (const float*)d_in[13];
    const float* g1 = (const float*)d_in[14];
    const float* be1 = (const float*)d_in[15];
    const float* g2 = (const float*)d_in[16];
    const float* be2 = (const float*)d_in[17];

    const size_t SZ = (size_t)8 * 4096 * 256;
    float* ws  = (float*)d_ws;
    float* KVb = ws;                          // 65536
    float* Ksb = KVb + 65536;                 // 2048
    float* Pkv = Ksb + 2048;                  // 2,097,152 (64 nh x 32 sp x 1024)
    float* Pks = Pkv + 2097152;               // 65536
    bf16*  Wt  = (bf16*)(Pks + 65536);        // 2,097,152 bf16
    bf16*  Xb  = Wt + 2097152;                // SZ bf16 (residual stream)
    bf16*  P2b = Xb + SZ;
    bf16*  Qb  = P2b + SZ;                    // also O-GEMM / FFN2 temp output
    bf16*  Kb  = Qb + SZ;
    bf16*  Vb  = Kb + SZ;
    bf16*  Bb  = Kb;                          // alias: K dead after kv_prep
    bf16*  Hb  = Kb;                          // alias: FFN hidden spans Kb+Vb

    wt_conv<<<dim3(16, 16, 24), dim3(32, 32), 0, stream>>>(Wq, Wk, Wv, Wo, W1, W2, Wt);
    encode_kernel<<<dim3(128, 8, 8), dim3(32, 32), 0, stream>>>(ref, srcf, Xb, P2b);

    for (int L = 0; L < 4; ++L) {
        const bf16* WtL = Wt + (size_t)L * 524288;
        const bf16* Akv = (L & 1) ? P2b : Xb;
        gemm_qkv<<<dim3(6, 256), 256, 0, stream>>>(Xb, Akv, WtL,
                                                   bq + L * 256, bk + L * 256, bv + L * 256,
                                                   Qb, Kb, Vb);
        kv_prep_part<<<dim3(32, 64), 256, 0, stream>>>(Kb, Vb, Pkv, Pks);
        kv_reduce<<<64, 256, 0, stream>>>(Pkv, Pks, KVb, Ksb);
        attn_apply<<<1024, 256, 0, stream>>>(Qb, KVb, Ksb, Bb);
        gemm_mfma<0><<<dim3(2, 256), 256, 0, stream>>>(Bb, WtL + 196608, bo + L * 256, Qb, 256, 256);
        ln_res<<<8192, 256, 0, stream>>>(Xb, Qb, g1 + L * 256, be1 + L * 256);
        gemm_mfma<1><<<dim3(4, 256), 256, 0, stream>>>(Xb, WtL + 262144, b1 + L * 512, Hb, 512, 256);
        gemm_mfma<0><<<dim3(2, 256), 256, 0, stream>>>(Hb, WtL + 393216, b2 + L * 256, Qb, 256, 512);
        ln_res<<<8192, 256, 0, stream>>>(Xb, Qb, g2 + L * 256, be2 + L * 256);
    }

    store_kernel<<<dim3(128, 8, 8), dim3(32, 32), 0, stream>>>(Xb, (float*)d_out);
}